// Round 9
// baseline (258.941 us; speedup 1.0000x reference)
//
#include <hip/hip_runtime.h>
#include <stdint.h>
#include <math.h>

#define NLEV 5
#define NIMG 16
#define NCLS 80
#define TOPK 1000
#define MTOT 5000
#define LPAD 1024
#define BINBCAP 4096
#define NBINS 288
#define BIN0 7846
#define OUTK 100
#define CHUNK 16384
#define NCHUNK 1632
#define PCAP_MAIN 1024
#define PCAP_BND 2048
#define CCAP 512

__device__ __constant__ int c_HW[NLEV]   = {15200, 3800, 950, 247, 70};
__device__ __constant__ int c_E[NLEV]    = {1216000, 304000, 76000, 19760, 5600};
__device__ __constant__ int c_cpr[NLEV]  = {75, 19, 5, 2, 1};            // chunks per (img,level) row
__device__ __constant__ int c_cbase[NLEV + 1] = {0, 1200, 1504, 1584, 1616, 1632};

struct Params {
    const float* cls[NLEV];
    const float* reg[NLEV];
    const float* anc[NLEV];
    const int* imsize;
};

// ---- shared decode (must be used identically by k_krsort and k_merge) ----
__device__ inline void decode_entry(const Params& P, int img, int lvl, uint32_t idx,
                                    float bclip[4], int* cls_out, bool* nonempty) {
    int HW = c_HW[lvl];
    int loc = (int)idx / NCLS;
    int c = (int)idx - loc * NCLS;
    const float* a = P.anc[lvl] + 4 * loc;
    float a0 = a[0], a1 = a[1], a2 = a[2], a3 = a[3];
    const float* rg = P.reg[lvl] + (size_t)img * 4 * HW + loc;
    float d0 = rg[0], d1 = rg[HW], d2 = rg[2 * HW], d3 = rg[3 * HW];
    float w = a2 - a0 + 1.0f, h = a3 - a1 + 1.0f;
    float cx = a0 + 0.5f * w, cy = a1 + 0.5f * h;
    float dx = d0 / 10.0f, dy = d1 / 10.0f;
    const float SCALE_CLAMP = 4.135166556742356f;
    float dw = fminf(d2 / 5.0f, SCALE_CLAMP);
    float dh = fminf(d3 / 5.0f, SCALE_CLAMP);
    float pcx = dx * w + cx, pcy = dy * h + cy;
    float pw = (float)exp((double)dw) * w;
    float ph = (float)exp((double)dh) * h;
    float x1 = pcx - 0.5f * (pw - 1.0f), y1 = pcy - 0.5f * (ph - 1.0f);
    float x2 = pcx + 0.5f * (pw - 1.0f), y2 = pcy + 0.5f * (ph - 1.0f);
    float Hs = (float)P.imsize[img * 2 + 0];
    float Ws = (float)P.imsize[img * 2 + 1];
    float x1c = fminf(fmaxf(x1, 0.0f), Ws);
    float y1c = fminf(fmaxf(y1, 0.0f), Hs);
    float x2c = fminf(fmaxf(x2, 0.0f), Ws);
    float y2c = fminf(fmaxf(y2, 0.0f), Hs);
    bclip[0] = x1c; bclip[1] = y1c; bclip[2] = x2c; bclip[3] = y2c;
    *cls_out = c;
    *nonempty = ((x2c - x1c) > 0.0f) && ((y2c - y1c) > 0.0f);
}

__device__ inline float sigmoid_f(float x) {
    return (float)(1.0 / (1.0 + exp(-(double)x)));
}

// ordered-uint <-> float (monotone bijection) for threshold bisection
__device__ inline uint32_t f2o(float f) {
    uint32_t b = __float_as_uint(f);
    return (b & 0x80000000u) ? ~b : (b | 0x80000000u);
}
__device__ inline float o2f(uint32_t o) {
    uint32_t b = (o & 0x80000000u) ? (o & 0x7FFFFFFFu) : ~o;
    return __uint_as_float(b);
}

// chunk -> (level, img, element range) mapping shared by k_hist / k_pass2
__device__ inline void chunk_map(int bid, int* lvl, int* img, int* start, int* end) {
    int l = 0;
#pragma unroll
    for (int q = 1; q < NLEV; q++) if (bid >= c_cbase[q]) l = q;
    int r = bid - c_cbase[l];
    int cpr = c_cpr[l];
    int im = r / cpr;
    int ch = r - im * cpr;
    int E = c_E[l];
    int st = ch * CHUNK;
    *lvl = l; *img = im; *start = st; *end = min(st + CHUNK, E);
}

// ---- K0: per-bin minimal-logit thresholds T[b] (monotone bisection) ----
__global__ void k_thr(float* T) {
    int b = blockIdx.x * blockDim.x + threadIdx.x;
    if (b >= NBINS) return;
    uint32_t lo = f2o(-4.0f), hi = f2o(20.0f);
    while (hi - lo > 1u) {
        uint32_t mid = lo + ((hi - lo) >> 1);
        float xm = o2f(mid);
        float s = sigmoid_f(xm);
        bool pass = (s > 0.05f) && (((int)(__float_as_uint(s) >> 17) - BIN0) >= b);
        if (pass) hi = mid; else lo = mid;
    }
    float xr = o2f(hi);
    float sv = sigmoid_f(xr);
    bool ok = (sv > 0.05f) && (((int)(__float_as_uint(sv) >> 17) - BIN0) >= b);
    T[b] = ok ? xr : __uint_as_float(0x7F800000u);   // unreachable bins -> +INF
}

// ---- K1: per-chunk private histogram; 4x-unrolled loads for MLP ----
__global__ __launch_bounds__(256) void k_hist(Params P, const float* T, uint32_t* histB) {
    __shared__ uint32_t lh[NBINS];
    __shared__ float sT[NBINS];
    int l, img, start, end;
    chunk_map(blockIdx.x, &l, &img, &start, &end);
    for (int b = threadIdx.x; b < NBINS; b += 256) { lh[b] = 0; sT[b] = T[b]; }
    __syncthreads();
    float t0 = sT[0];
    const float4* p = (const float4*)(P.cls[l] + (size_t)img * c_E[l] + start);
    int n4 = (end - start) >> 2;
    for (int base = 0; base < n4; base += 1024) {
        float4 r[4];
#pragma unroll
        for (int u = 0; u < 4; u++) {
            int off = base + u * 256 + threadIdx.x;
            r[u] = (off < n4) ? p[off] : make_float4(-1e30f, -1e30f, -1e30f, -1e30f);
        }
#pragma unroll
        for (int u = 0; u < 4; u++) {
            float xs[4] = {r[u].x, r[u].y, r[u].z, r[u].w};
#pragma unroll
            for (int k = 0; k < 4; k++) {
                float xv = xs[k];
                if (xv >= t0) {                       // exact pass-threshold
                    float se = 1.0f / (1.0f + __expf(-xv));   // estimator only
                    int b = (int)(__float_as_uint(se) >> 17) - BIN0;
                    b = min(max(b, 0), NBINS - 1);
                    while (b > 0 && xv < sT[b]) b--;          // exact fix-up:
                    while (b + 1 < NBINS && xv >= sT[b + 1]) b++;  // T[b]<=x<T[b+1]
                    atomicAdd(&lh[b], 1u);
                }
            }
        }
    }
    __syncthreads();
    uint32_t* hb = histB + (size_t)blockIdx.x * NBINS;
    for (int b = threadIdx.x; b < NBINS; b += 256) hb[b] = lh[b];
}

// ---- K2: reduce per-chunk histograms, scan top-down for boundary bin ----
__global__ __launch_bounds__(256) void k_scan(const uint32_t* histB, int* sel) {
    __shared__ uint32_t lh[NBINS];
    int row = blockIdx.x;
    int l = row / NIMG, img = row - l * NIMG;
    int cb = c_cbase[l] + img * c_cpr[l];
    int nc = c_cpr[l];
    for (int b = threadIdx.x; b < NBINS; b += 256) {
        uint32_t s = 0;
        for (int c = 0; c < nc; c++) s += histB[(size_t)(cb + c) * NBINS + b];
        lh[b] = s;
    }
    __syncthreads();
    if (threadIdx.x == 0) {
        int cum = 0, B = -1, need = 0, cab = 0;
        for (int b = NBINS - 1; b >= 0; b--) {
            int c = (int)lh[b];
            if (cum + c >= TOPK) { B = b; cab = cum; need = TOPK - cum; break; }
            cum += c;
        }
        if (B < 0) { cab = cum; need = 0; }
        sel[row * 4 + 0] = B;
        sel[row * 4 + 1] = cab;
        sel[row * 4 + 2] = need;
        sel[row * 4 + 3] = cum;
    }
}

// ---- K3: compact candidates; LDS-privatized; 4x-unrolled loads ----
__global__ __launch_bounds__(256) void k_pass2(Params P, const int* sel, const float* T,
                                               uint32_t* outCand, uint32_t* outCount,
                                               uint32_t* binB, uint32_t* binBCnt) {
    __shared__ uint64_t smain[PCAP_MAIN];
    __shared__ uint64_t sbnd[PCAP_BND];
    __shared__ uint32_t cnt2[2];
    __shared__ uint32_t base2[2];
    int l, img, start, end;
    chunk_map(blockIdx.x, &l, &img, &start, &end);
    int row = l * NIMG + img;
    int B = sel[row * 4 + 0];
    float xt = T[max(B, 0)];
    int HW = c_HW[l];
    if (threadIdx.x < 2) cnt2[threadIdx.x] = 0;
    __syncthreads();
    const float4* p = (const float4*)(P.cls[l] + (size_t)img * c_E[l] + start);
    int n4 = (end - start) >> 2;
    for (int base = 0; base < n4; base += 1024) {
        float4 r[4];
#pragma unroll
        for (int u = 0; u < 4; u++) {
            int off = base + u * 256 + threadIdx.x;
            r[u] = (off < n4) ? p[off] : make_float4(-1e30f, -1e30f, -1e30f, -1e30f);
        }
#pragma unroll
        for (int u = 0; u < 4; u++) {
            int off = base + u * 256 + threadIdx.x;
            float xs[4] = {r[u].x, r[u].y, r[u].z, r[u].w};
#pragma unroll
            for (int k = 0; k < 4; k++) {
                float xv = xs[k];
                if (xv >= xt) {                       // implies s>0.05f && bin>=B
                    float s = sigmoid_f(xv);          // exact bits for the key
                    uint32_t bits = __float_as_uint(s);
                    int bin = (int)(bits >> 17) - BIN0;
                    int q2 = start + off * 4 + k;     // c*HW + p layout
                    int c = q2 / HW;
                    int pidx = q2 - c * HW;
                    uint32_t idx = (uint32_t)(pidx * NCLS + c);
                    uint64_t rec = ((uint64_t)bits << 32) | idx;
                    if (bin > B) {
                        uint32_t lp = atomicAdd(&cnt2[0], 1u);
                        if (lp < PCAP_MAIN) smain[lp] = rec;   // cab<=999 -> never overflows
                        else {
                            uint32_t pos = atomicAdd(&outCount[row], 1u);
                            if (pos < TOPK)
                                ((uint2*)outCand)[(size_t)row * TOPK + pos] = make_uint2(bits, idx);
                        }
                    } else {
                        uint32_t lp = atomicAdd(&cnt2[1], 1u);
                        if (lp < PCAP_BND) sbnd[lp] = rec;
                        else {
                            uint32_t p2 = atomicAdd(&binBCnt[row], 1u);
                            if (p2 < BINBCAP)
                                ((uint2*)binB)[(size_t)row * BINBCAP + p2] = make_uint2(bits, idx);
                        }
                    }
                }
            }
        }
    }
    __syncthreads();
    if (threadIdx.x == 0) base2[0] = atomicAdd(&outCount[row], min(cnt2[0], (uint32_t)PCAP_MAIN));
    if (threadIdx.x == 1) base2[1] = atomicAdd(&binBCnt[row], min(cnt2[1], (uint32_t)PCAP_BND));
    __syncthreads();
    uint32_t n0 = min(cnt2[0], (uint32_t)PCAP_MAIN);
    for (uint32_t i = threadIdx.x; i < n0; i += 256) {
        uint32_t pos = base2[0] + i;
        if (pos < TOPK) {
            uint64_t r = smain[i];
            ((uint2*)outCand)[(size_t)row * TOPK + pos] = make_uint2((uint32_t)(r >> 32), (uint32_t)r);
        }
    }
    uint32_t n1 = min(cnt2[1], (uint32_t)PCAP_BND);
    for (uint32_t i = threadIdx.x; i < n1; i += 256) {
        uint32_t pos = base2[1] + i;
        if (pos < BINBCAP) {
            uint64_t r = sbnd[i];
            ((uint2*)binB)[(size_t)row * BINBCAP + pos] = make_uint2((uint32_t)(r >> 32), (uint32_t)r);
        }
    }
}

// ---- K4: exact sort of boundary bin (dynamic pow2 size), append winners ----
__global__ __launch_bounds__(256) void k_selsort(const int* sel, const uint32_t* binB,
                                                 const uint32_t* binBCnt, uint32_t* outCand) {
    __shared__ uint64_t sk[BINBCAP];
    int row = blockIdx.x;
    int need = sel[row * 4 + 2];
    int cab = sel[row * 4 + 1];
    if (need <= 0) return;
    int cnt = min((int)binBCnt[row], BINBCAP);
    int N = 64; while (N < cnt) N <<= 1;     // dynamic sort size
    for (int i = threadIdx.x; i < N; i += blockDim.x) {
        uint64_t key = ~0ULL;
        if (i < cnt) {
            uint32_t b = binB[((size_t)row * BINBCAP + i) * 2 + 0];
            uint32_t idx = binB[((size_t)row * BINBCAP + i) * 2 + 1];
            key = ((uint64_t)(uint32_t)(~b) << 32) | idx;   // value desc, idx asc
        }
        sk[i] = key;
    }
    __syncthreads();
    for (int k = 2; k <= N; k <<= 1) {
        for (int j = k >> 1; j > 0; j >>= 1) {
            for (int i = threadIdx.x; i < N; i += blockDim.x) {
                int ixj = i ^ j;
                if (ixj > i) {
                    uint64_t A = sk[i], Bv = sk[ixj];
                    bool up = ((i & k) == 0);
                    if (up ? (A > Bv) : (A < Bv)) { sk[i] = Bv; sk[ixj] = A; }
                }
            }
            __syncthreads();
        }
    }
    int take = min(need, cnt);
    for (int i = threadIdx.x; i < take; i += blockDim.x) {
        uint64_t k = sk[i];
        uint32_t idx = (uint32_t)(k & 0xFFFFFFFFu);
        uint32_t bits = ~((uint32_t)(k >> 32));
        int pos = cab + i;
        outCand[((size_t)row * TOPK + pos) * 2 + 0] = bits;
        outCand[((size_t)row * TOPK + pos) * 2 + 1] = idx;
    }
}

// ---- K5 (fused keys+rsort): build 1024 keys in LDS, bitonic sort, store ----
__global__ __launch_bounds__(256) void k_krsort(Params P, const uint32_t* outCand,
                                                const int* sel, const uint32_t* binBCnt,
                                                uint64_t* keys) {
    __shared__ uint64_t sk[LPAD];
    int blk = blockIdx.x;            // 0..79 -> (img, lvl); keys layout [img][lvl][1024]
    int img = blk / NLEV, lvl = blk - img * NLEV;
    int row = lvl * NIMG + img;
    int Bq = sel[row * 4 + 0], cab = sel[row * 4 + 1];
    int need = sel[row * 4 + 2], cum = sel[row * 4 + 3];
    int cnt = min((int)binBCnt[row], BINBCAP);
    int filled = (Bq < 0) ? cum : (cab + min(need, cnt));
    for (int slot = threadIdx.x; slot < LPAD; slot += 256) {
        uint64_t key;
        if (slot >= TOPK) key = ~0ULL;
        else {
            uint32_t bits = 0, idx = 0;
            if (slot < filled) {
                uint2 r = ((const uint2*)outCand)[(size_t)row * TOPK + slot];
                bits = r.x; idx = r.y;
            }
            uint32_t be = 0;
            if (bits != 0) {
                float bc[4]; int cc; bool ne;
                decode_entry(P, img, lvl, idx, bc, &cc, &ne);
                if (ne) be = bits;
            }
            key = ((uint64_t)(uint32_t)(~be) << 24) | ((uint64_t)lvl << 21) | (uint64_t)idx;
        }
        sk[slot] = key;
    }
    __syncthreads();
    for (int k = 2; k <= LPAD; k <<= 1) {
        for (int j = k >> 1; j > 0; j >>= 1) {
            for (int i = threadIdx.x; i < LPAD; i += 256) {
                int ixj = i ^ j;
                if (ixj > i) {
                    uint64_t A = sk[i], Bv = sk[ixj];
                    bool up = ((i & k) == 0);
                    if (up ? (A > Bv) : (A < Bv)) { sk[i] = Bv; sk[ixj] = A; }
                }
            }
            __syncthreads();
        }
    }
    uint64_t* g = keys + (size_t)blk * LPAD;
    for (int i = threadIdx.x; i < LPAD; i += 256) g[i] = sk[i];
}

// ---- K6 (fused merge+prep): rank-merge 5 sorted lists, decode, write ----
// Exact: keys never tie cross-list (key embeds lvl); within-list rank uses
// position, so ranks form a bijection onto [0, 5000).
__global__ __launch_bounds__(1024) void k_merge(Params P, const uint64_t* keys,
                                                float4* boff, float* area, float4* bclip,
                                                float* scs, int* clss,
                                                uint8_t* keepB, uint8_t* clsB) {
    __shared__ uint64_t sl[NLEV * LPAD];   // 40 KB
    int img = blockIdx.x;
    const uint64_t* g = keys + (size_t)img * NLEV * LPAD;
    for (int i = threadIdx.x; i < NLEV * LPAD; i += 1024) sl[i] = g[i];
    __syncthreads();
    const int gb = img * MTOT;
    for (int e = threadIdx.x; e < NLEV * LPAD; e += 1024) {
        int l = e >> 10, i = e & (LPAD - 1);
        if (i >= TOPK) continue;           // sentinels sort to tail, never placed
        uint64_t K = sl[e];
        int rank = i;
#pragma unroll
        for (int l2 = 0; l2 < NLEV; l2++) {
            if (l2 == l) continue;
            const uint64_t* s2 = &sl[l2 << 10];
            int lo = 0, hi = TOPK;
            while (lo < hi) {
                int mid = (lo + hi) >> 1;
                if (s2[mid] < K) lo = mid + 1; else hi = mid;
            }
            rank += lo;
        }
        // decode & write NMS-ready arrays directly at [rank] (was k_prep)
        uint32_t bits = ~((uint32_t)(K >> 24));
        int lvl = (int)((K >> 21) & 7);
        uint32_t idx = (uint32_t)(K & 0x1FFFFF);
        float bc[4]; int cc; bool ne;
        decode_entry(P, img, lvl, idx, bc, &cc, &ne);
        float sc = 0.0f;
        if (bits != 0) {
            float s = __uint_as_float(bits);
            sc = sqrtf(fmaxf(s, 1e-12f));
        }
        float off = (float)cc * 2000.0f;
        float b0 = bc[0] + off, b1 = bc[1] + off, b2 = bc[2] + off, b3 = bc[3] + off;
        int t = gb + rank;
        boff[t] = make_float4(b0, b1, b2, b3);
        area[t] = (b2 - b0) * (b3 - b1);
        bclip[t] = make_float4(bc[0], bc[1], bc[2], bc[3]);
        scs[t] = sc;
        clss[t] = cc;
        keepB[t] = 0;
        clsB[t] = (sc != 0.0f) ? (uint8_t)cc : (uint8_t)0xFF;   // 0xFF = invalid
    }
}

// ---- K7: per-(img,class) greedy NMS; byte-map bucket build (L1-resident) ----
// Cross-class IoU is exactly 0 (offset 2000 > max coord 1216), so greedy
// keep/suppress decomposes exactly by class; bucket preserves rank order.
__global__ __launch_bounds__(64) void k_cnms(const float4* boff, const float* area,
                                             const uint8_t* clsB, uint8_t* keepB) {
    __shared__ float sx1[CCAP], sy1[CCAP], sx2[CCAP], sy2[CCAP], sar[CCAP];
    __shared__ uint16_t ranks[CCAP];
    int img = blockIdx.x / NCLS;
    int cls = blockIdx.x - img * NCLS;
    int lane = threadIdx.x;
    const int gb = img * MTOT;

    // ---- bucket build: scan 5000 class bytes (uchar4/lane), ballot-compact ----
    int n = 0;
    const uchar4* cp = (const uchar4*)(clsB + gb);      // 1250 uchar4 = 5 KB
    for (int base = 0; base < 1250; base += 64) {
        int q = base + lane;
        uchar4 cv = (q < 1250) ? cp[q] : make_uchar4(255, 255, 255, 255);
#pragma unroll
        for (int b = 0; b < 4; b++) {
            int cb = (b == 0) ? cv.x : (b == 1) ? cv.y : (b == 2) ? cv.z : cv.w;
            bool pred = (cb == cls);
            uint64_t mask = __ballot(pred);
            int pos = n + (int)__popcll(mask & ((1ULL << lane) - 1ULL));
            if (pred && pos < CCAP) ranks[pos] = (uint16_t)(q * 4 + b);
            n += (int)__popcll(mask);
        }
    }
    n = min(n, CCAP);
    __syncthreads();
    if (n == 0) return;

    // ---- gather bucket boxes (n ~ 62 scattered loads, L2-resident) ----
    for (int i = lane; i < n; i += 64) {
        int t = ranks[i];
        float4 b = boff[gb + t];
        sx1[i] = b.x; sy1[i] = b.y; sx2[i] = b.z; sy2[i] = b.w;
        sar[i] = area[gb + t];
    }
    __syncthreads();

    // ---- greedy scan: masks replicated in registers via ballot ----
    uint64_t m[CCAP / 64];
#pragma unroll
    for (int c = 0; c < CCAP / 64; c++) m[c] = 0ULL;
#pragma unroll
    for (int c = 0; c < CCAP / 64; c++) {
        if (c * 64 >= n) break;
        for (int ii = 0; ii < 64; ii++) {
            int i = c * 64 + ii;
            if (i >= n) break;
            if ((m[c] >> ii) & 1ULL) continue;
            float bx1 = sx1[i], by1 = sy1[i], bx2 = sx2[i], by2 = sy2[i], bai = sar[i];
            if (lane == 0) keepB[gb + ranks[i]] = 1;
#pragma unroll
            for (int c2 = 0; c2 < CCAP / 64; c2++) {
                if (c2 < c) continue;               // j > i pruning (const-folds)
                if (c2 * 64 >= n) break;
                int j = c2 * 64 + lane;
                float xx1 = fmaxf(bx1, sx1[j]), yy1 = fmaxf(by1, sy1[j]);
                float xx2 = fminf(bx2, sx2[j]), yy2 = fminf(by2, sy2[j]);
                float inter = fmaxf(xx2 - xx1, 0.0f) * fmaxf(yy2 - yy1, 0.0f);
                float iou = inter / (bai + sar[j] - inter + 1e-9f);
                bool pr = (j > i) && (j < n) && (iou > 0.6f);
                m[c2] |= __ballot(pr);
            }
        }
    }
}

// ---- K8: per-image output: first 100 kept (rank order) + filler ----
__global__ __launch_bounds__(64) void k_out(const float4* bclip, const float* scs,
                                            const int* clss, const uint8_t* keepB, float* out) {
    __shared__ int keptIdx[OUTK];
    int img = blockIdx.x;
    int lane = threadIdx.x;
    const int gb = img * MTOT;
    int kc = 0;
    for (int base = 0; base < MTOT && kc < OUTK; base += 64) {
        int t = base + lane;
        bool pred = (t < MTOT) && (keepB[gb + t] != 0);
        uint64_t mask = __ballot(pred);
        int pos = kc + (int)__popcll(mask & ((1ULL << lane) - 1ULL));
        if (pred && pos < OUTK) keptIdx[pos] = t;
        kc = min(kc + (int)__popcll(mask), OUTK);
    }
    // filler: first non-kept entries in index order, score forced to 0
    for (int base = 0; base < MTOT && kc < OUTK; base += 64) {
        int t = base + lane;
        bool pred = (t < MTOT) && (keepB[gb + t] == 0);
        uint64_t mask = __ballot(pred);
        int pos = kc + (int)__popcll(mask & ((1ULL << lane) - 1ULL));
        if (pred && pos < OUTK) keptIdx[pos] = t | (1 << 30);
        kc = min(kc + (int)__popcll(mask), OUTK);
    }
    __syncthreads();
    for (int t = lane; t < OUTK; t += 64) {
        int ke = keptIdx[t];
        bool fil = (ke >> 30) & 1;
        int e = ke & 0x3FFFFFFF;
        float4 b = bclip[gb + e];
        out[((size_t)img * OUTK + t) * 4 + 0] = b.x;
        out[((size_t)img * OUTK + t) * 4 + 1] = b.y;
        out[((size_t)img * OUTK + t) * 4 + 2] = b.z;
        out[((size_t)img * OUTK + t) * 4 + 3] = b.w;
        out[NIMG * OUTK * 4 + img * OUTK + t] = fil ? 0.0f : scs[gb + e];
        out[NIMG * OUTK * 4 + NIMG * OUTK + img * OUTK + t] = (float)clss[gb + e];
    }
}

extern "C" void kernel_launch(void* const* d_in, const int* in_sizes, int n_in,
                              void* d_out, int out_size, void* d_ws, size_t ws_size,
                              hipStream_t stream) {
    Params P;
    for (int l = 0; l < 5; l++) {
        P.cls[l] = (const float*)d_in[l * 3 + 0];
        P.reg[l] = (const float*)d_in[l * 3 + 1];
        P.anc[l] = (const float*)d_in[l * 3 + 2];
    }
    P.imsize = (const int*)d_in[15];

    char* w = (char*)d_ws;
    // Lifetime-aliased layout (total 4,978,432 bytes):
    //  region A [0..3,520,000): histB (K1->K2) | binB (K3->K4) | NMS arrays (K6->K8)
    uint32_t* histB    = (uint32_t*)(w + 0);        // 1632*288*4 = 1,880,064
    uint32_t* binB     = (uint32_t*)(w + 0);        // 80*4096*8  = 2,621,440
    float4*   boff     = (float4*)(w + 0);          // 1,280,000
    float*    area     = (float*)(w + 1280000);     // 320,000 -> 1,600,000
    float4*   bclipb   = (float4*)(w + 1600000);    // 1,280,000 -> 2,880,000
    float*    scs      = (float*)(w + 2880000);     // 320,000 -> 3,200,000
    int*      clss     = (int*)(w + 3200000);       // 320,000 -> 3,520,000
    int*      sel      = (int*)(w + 3520000);       // 1,280 -> 3,521,280
    uint32_t* outCount = (uint32_t*)(w + 3521280);  // 320 -> 3,521,600
    uint32_t* binBCnt  = (uint32_t*)(w + 3521600);  // 320 -> 3,521,920
    float*    T        = (float*)(w + 3521920);     // 1,152 -> 3,523,072
    uint32_t* outCand  = (uint32_t*)(w + 3523072);  // 640,000 -> 4,163,072
    uint64_t* keys     = (uint64_t*)(w + 4163072);  // 16*5120*8 = 655,360 -> 4,818,432
    uint8_t*  keepB    = (uint8_t*)(w + 4818432);   // 16*5000   = 80,000  -> 4,898,432
    uint8_t*  clsB     = (uint8_t*)(w + 4898432);   // 16*5000   = 80,000  -> 4,978,432

    hipMemsetAsync(w + 3521280, 0, 640, stream);    // outCount + binBCnt only

    k_thr<<<(NBINS + 63) / 64, 64, 0, stream>>>(T);
    k_hist<<<NCHUNK, 256, 0, stream>>>(P, T, histB);
    k_scan<<<80, 256, 0, stream>>>(histB, sel);
    k_pass2<<<NCHUNK, 256, 0, stream>>>(P, sel, T, outCand, outCount, binB, binBCnt);
    k_selsort<<<80, 256, 0, stream>>>(sel, binB, binBCnt, outCand);
    k_krsort<<<NIMG * NLEV, 256, 0, stream>>>(P, outCand, sel, binBCnt, keys);
    k_merge<<<NIMG, 1024, 0, stream>>>(P, keys, boff, area, bclipb, scs, clss, keepB, clsB);
    k_cnms<<<NIMG * NCLS, 64, 0, stream>>>(boff, area, clsB, keepB);
    k_out<<<NIMG, 64, 0, stream>>>(bclipb, scs, clss, keepB, (float*)d_out);
}

// Round 10
// 257.740 us; speedup vs baseline: 1.0047x; 1.0047x over previous
//
#include <hip/hip_runtime.h>
#include <stdint.h>
#include <math.h>

#define NLEV 5
#define NIMG 16
#define NCLS 80
#define TOPK 1000
#define MTOT 5000
#define LPAD 1024
#define BINBCAP 4096
#define NBINS 288
#define BIN0 7846
#define OUTK 100
#define CHUNK 8192
#define NCHUNK 3216
#define PCAP_MAIN 1024
#define PCAP_BND 2048
#define CCAP 512

__device__ __constant__ int c_HW[NLEV]   = {15200, 3800, 950, 247, 70};
__device__ __constant__ int c_E[NLEV]    = {1216000, 304000, 76000, 19760, 5600};
__device__ __constant__ int c_cpr[NLEV]  = {149, 38, 10, 3, 1};          // 8192-chunks per (img,level) row
__device__ __constant__ int c_cbase[NLEV + 1] = {0, 2384, 2992, 3152, 3200, 3216};

struct Params {
    const float* cls[NLEV];
    const float* reg[NLEV];
    const float* anc[NLEV];
    const int* imsize;
};

// ---- shared decode (must be used identically by k_selkr and k_merge) ----
__device__ inline void decode_entry(const Params& P, int img, int lvl, uint32_t idx,
                                    float bclip[4], int* cls_out, bool* nonempty) {
    int HW = c_HW[lvl];
    int loc = (int)idx / NCLS;
    int c = (int)idx - loc * NCLS;
    const float* a = P.anc[lvl] + 4 * loc;
    float a0 = a[0], a1 = a[1], a2 = a[2], a3 = a[3];
    const float* rg = P.reg[lvl] + (size_t)img * 4 * HW + loc;
    float d0 = rg[0], d1 = rg[HW], d2 = rg[2 * HW], d3 = rg[3 * HW];
    float w = a2 - a0 + 1.0f, h = a3 - a1 + 1.0f;
    float cx = a0 + 0.5f * w, cy = a1 + 0.5f * h;
    float dx = d0 / 10.0f, dy = d1 / 10.0f;
    const float SCALE_CLAMP = 4.135166556742356f;
    float dw = fminf(d2 / 5.0f, SCALE_CLAMP);
    float dh = fminf(d3 / 5.0f, SCALE_CLAMP);
    float pcx = dx * w + cx, pcy = dy * h + cy;
    float pw = (float)exp((double)dw) * w;
    float ph = (float)exp((double)dh) * h;
    float x1 = pcx - 0.5f * (pw - 1.0f), y1 = pcy - 0.5f * (ph - 1.0f);
    float x2 = pcx + 0.5f * (pw - 1.0f), y2 = pcy + 0.5f * (ph - 1.0f);
    float Hs = (float)P.imsize[img * 2 + 0];
    float Ws = (float)P.imsize[img * 2 + 1];
    float x1c = fminf(fmaxf(x1, 0.0f), Ws);
    float y1c = fminf(fmaxf(y1, 0.0f), Hs);
    float x2c = fminf(fmaxf(x2, 0.0f), Ws);
    float y2c = fminf(fmaxf(y2, 0.0f), Hs);
    bclip[0] = x1c; bclip[1] = y1c; bclip[2] = x2c; bclip[3] = y2c;
    *cls_out = c;
    *nonempty = ((x2c - x1c) > 0.0f) && ((y2c - y1c) > 0.0f);
}

__device__ inline float sigmoid_f(float x) {
    return (float)(1.0 / (1.0 + exp(-(double)x)));
}

// ordered-uint <-> float (monotone bijection) for threshold bisection
__device__ inline uint32_t f2o(float f) {
    uint32_t b = __float_as_uint(f);
    return (b & 0x80000000u) ? ~b : (b | 0x80000000u);
}
__device__ inline float o2f(uint32_t o) {
    uint32_t b = (o & 0x80000000u) ? (o & 0x7FFFFFFFu) : ~o;
    return __uint_as_float(b);
}

// chunk -> (level, img, element range) mapping shared by k_hist / k_pass2
__device__ inline void chunk_map(int bid, int* lvl, int* img, int* start, int* end) {
    int l = 0;
#pragma unroll
    for (int q = 1; q < NLEV; q++) if (bid >= c_cbase[q]) l = q;
    int r = bid - c_cbase[l];
    int cpr = c_cpr[l];
    int im = r / cpr;
    int ch = r - im * cpr;
    int E = c_E[l];
    int st = ch * CHUNK;
    *lvl = l; *img = im; *start = st; *end = min(st + CHUNK, E);
}

// ---- K0: thresholds T[b] + zero hist + zero counters (fused init) ----
__global__ __launch_bounds__(320) void k_thr(float* T, uint32_t* hist, uint32_t* cnts) {
    int b = blockIdx.x;
    int t = threadIdx.x;
    if (t < NBINS) hist[b * NBINS + t] = 0;
    if (b == 1 && t < 160) cnts[t] = 0;            // outCount[80] + binBCnt[80]
    if (b == 0 && t < NBINS) {
        uint32_t lo = f2o(-4.0f), hi = f2o(20.0f);
        while (hi - lo > 1u) {
            uint32_t mid = lo + ((hi - lo) >> 1);
            float xm = o2f(mid);
            float s = sigmoid_f(xm);
            bool pass = (s > 0.05f) && (((int)(__float_as_uint(s) >> 17) - BIN0) >= t);
            if (pass) hi = mid; else lo = mid;
        }
        float xr = o2f(hi);
        float sv = sigmoid_f(xr);
        bool ok = (sv > 0.05f) && (((int)(__float_as_uint(sv) >> 17) - BIN0) >= t);
        T[t] = ok ? xr : __uint_as_float(0x7F800000u);
    }
}

// ---- K1: per-chunk hist (atomic row flush) + per-thread segment-max u16 ----
// Thread owns 32 consecutive elements (8 float4). segMax16 = round-UP-to-
// upper-16-bits bound of the segment max: reconstructed value >= true max,
// so pass2 skipping ub < xt never drops a passing element.
__global__ __launch_bounds__(256) void k_hist(Params P, const float* T, uint32_t* hist,
                                              uint16_t* segMax16) {
    __shared__ uint32_t lh[NBINS];
    __shared__ float sT[NBINS];
    int l, img, start, end;
    chunk_map(blockIdx.x, &l, &img, &start, &end);
    for (int b = threadIdx.x; b < NBINS; b += 256) { lh[b] = 0; sT[b] = T[b]; }
    __syncthreads();
    float t0 = sT[0];
    const float4* p = (const float4*)(P.cls[l] + (size_t)img * c_E[l] + start) + threadIdx.x * 8;
    int n4 = (end - start) >> 2;
    int b4 = threadIdx.x * 8;
    float4 r[8];
#pragma unroll
    for (int u = 0; u < 8; u++)
        r[u] = (b4 + u < n4) ? p[u] : make_float4(-1e30f, -1e30f, -1e30f, -1e30f);
    float mx = -1e30f;
#pragma unroll
    for (int u = 0; u < 8; u++)
        mx = fmaxf(mx, fmaxf(fmaxf(r[u].x, r[u].y), fmaxf(r[u].z, r[u].w)));
#pragma unroll
    for (int u = 0; u < 8; u++) {
        float xs[4] = {r[u].x, r[u].y, r[u].z, r[u].w};
#pragma unroll
        for (int k = 0; k < 4; k++) {
            float xv = xs[k];
            if (xv >= t0) {
                float se = 1.0f / (1.0f + __expf(-xv));   // estimator only
                int b = (int)(__float_as_uint(se) >> 17) - BIN0;
                b = min(max(b, 0), NBINS - 1);
                while (b > 0 && xv < sT[b]) b--;          // exact fix-up:
                while (b + 1 < NBINS && xv >= sT[b + 1]) b++;  // T[b]<=x<T[b+1]
                atomicAdd(&lh[b], 1u);
            }
        }
    }
    uint32_t mb = __float_as_uint(mx);
    uint16_t ub = (mx >= 0.0f) ? (uint16_t)((mb + 0xFFFFu) >> 16) : (uint16_t)(mb >> 16);
    segMax16[(size_t)blockIdx.x * 256 + threadIdx.x] = ub;
    __syncthreads();
    int row = l * NIMG + img;
    for (int b = threadIdx.x; b < NBINS; b += 256) {
        uint32_t c = lh[b];
        if (c) atomicAdd(&hist[row * NBINS + b], c);
    }
}

// ---- K2: scan per-row histogram top-down for boundary bin ----
__global__ __launch_bounds__(320) void k_scan(const uint32_t* hist, int* sel) {
    __shared__ uint32_t lh[NBINS];
    int row = blockIdx.x;
    if (threadIdx.x < NBINS) lh[threadIdx.x] = hist[row * NBINS + threadIdx.x];
    __syncthreads();
    if (threadIdx.x == 0) {
        int cum = 0, B = -1, need = 0, cab = 0;
        for (int b = NBINS - 1; b >= 0; b--) {
            int c = (int)lh[b];
            if (cum + c >= TOPK) { B = b; cab = cum; need = TOPK - cum; break; }
            cum += c;
        }
        if (B < 0) { cab = cum; need = 0; }
        sel[row * 4 + 0] = B;
        sel[row * 4 + 1] = cab;
        sel[row * 4 + 2] = need;
        sel[row * 4 + 3] = cum;
    }
}

// ---- K3: compact candidates; segment-max skip, LDS-privatized ----
__global__ __launch_bounds__(256) void k_pass2(Params P, const int* sel, const float* T,
                                               const uint16_t* segMax16,
                                               uint32_t* outCand, uint32_t* outCount,
                                               uint32_t* binB, uint32_t* binBCnt) {
    __shared__ uint64_t smain[PCAP_MAIN];
    __shared__ uint64_t sbnd[PCAP_BND];
    __shared__ uint32_t cnt2[2];
    __shared__ uint32_t base2[2];
    int l, img, start, end;
    chunk_map(blockIdx.x, &l, &img, &start, &end);
    int row = l * NIMG + img;
    int B = sel[row * 4 + 0];
    float xt = T[max(B, 0)];
    int HW = c_HW[l];
    if (threadIdx.x < 2) cnt2[threadIdx.x] = 0;
    __syncthreads();
    uint16_t ub = segMax16[(size_t)blockIdx.x * 256 + threadIdx.x];
    bool active = (__uint_as_float((uint32_t)ub << 16) >= xt);
    if (active) {
        const float4* p = (const float4*)(P.cls[l] + (size_t)img * c_E[l] + start) + threadIdx.x * 8;
        int n4 = (end - start) >> 2;
        int b4 = threadIdx.x * 8;
        float4 r[8];
#pragma unroll
        for (int u = 0; u < 8; u++)
            r[u] = (b4 + u < n4) ? p[u] : make_float4(-1e30f, -1e30f, -1e30f, -1e30f);
#pragma unroll
        for (int u = 0; u < 8; u++) {
            float xs[4] = {r[u].x, r[u].y, r[u].z, r[u].w};
#pragma unroll
            for (int k = 0; k < 4; k++) {
                float xv = xs[k];
                if (xv >= xt) {                       // implies s>0.05f && bin>=B
                    float s = sigmoid_f(xv);          // exact bits for the key
                    uint32_t bits = __float_as_uint(s);
                    int bin = (int)(bits >> 17) - BIN0;
                    int q2 = start + (b4 + u) * 4 + k;  // c*HW + p layout
                    int c = q2 / HW;
                    int pidx = q2 - c * HW;
                    uint32_t idx = (uint32_t)(pidx * NCLS + c);
                    uint64_t rec = ((uint64_t)bits << 32) | idx;
                    if (bin > B) {
                        uint32_t lp = atomicAdd(&cnt2[0], 1u);
                        if (lp < PCAP_MAIN) smain[lp] = rec;   // cab<=999 -> never overflows
                        else {
                            uint32_t pos = atomicAdd(&outCount[row], 1u);
                            if (pos < TOPK)
                                ((uint2*)outCand)[(size_t)row * TOPK + pos] = make_uint2(bits, idx);
                        }
                    } else {
                        uint32_t lp = atomicAdd(&cnt2[1], 1u);
                        if (lp < PCAP_BND) sbnd[lp] = rec;
                        else {
                            uint32_t p2 = atomicAdd(&binBCnt[row], 1u);
                            if (p2 < BINBCAP)
                                ((uint2*)binB)[(size_t)row * BINBCAP + p2] = make_uint2(bits, idx);
                        }
                    }
                }
            }
        }
    }
    __syncthreads();
    if (threadIdx.x == 0) base2[0] = atomicAdd(&outCount[row], min(cnt2[0], (uint32_t)PCAP_MAIN));
    if (threadIdx.x == 1) base2[1] = atomicAdd(&binBCnt[row], min(cnt2[1], (uint32_t)PCAP_BND));
    __syncthreads();
    uint32_t n0 = min(cnt2[0], (uint32_t)PCAP_MAIN);
    for (uint32_t i = threadIdx.x; i < n0; i += 256) {
        uint32_t pos = base2[0] + i;
        if (pos < TOPK) {
            uint64_t rr = smain[i];
            ((uint2*)outCand)[(size_t)row * TOPK + pos] = make_uint2((uint32_t)(rr >> 32), (uint32_t)rr);
        }
    }
    uint32_t n1 = min(cnt2[1], (uint32_t)PCAP_BND);
    for (uint32_t i = threadIdx.x; i < n1; i += 256) {
        uint32_t pos = base2[1] + i;
        if (pos < BINBCAP) {
            uint64_t rr = sbnd[i];
            ((uint2*)binB)[(size_t)row * BINBCAP + pos] = make_uint2((uint32_t)(rr >> 32), (uint32_t)rr);
        }
    }
}

// ---- K4 (fused selsort + keys + rsort): boundary sort in LDS, build 1024
//      keys (winners read from LDS, no global round-trip), sort, store ----
__global__ __launch_bounds__(256) void k_selkr(Params P, const uint32_t* outCand,
                                               const int* sel, const uint32_t* binBCnt,
                                               const uint32_t* binB, uint64_t* keys) {
    __shared__ uint64_t sk[BINBCAP];   // 32 KB: boundary-bin sort
    __shared__ uint64_t kk[LPAD];      // 8 KB: final key sort
    int blk = blockIdx.x;              // keys layout [img][lvl][1024]
    int img = blk / NLEV, lvl = blk - img * NLEV;
    int row = lvl * NIMG + img;
    int Bq = sel[row * 4 + 0], cab = sel[row * 4 + 1];
    int need = sel[row * 4 + 2], cum = sel[row * 4 + 3];
    int cnt = min((int)binBCnt[row], BINBCAP);
    int take = 0;
    if (need > 0) {
        int N = 64; while (N < cnt) N <<= 1;
        for (int i = threadIdx.x; i < N; i += 256) {
            uint64_t key = ~0ULL;
            if (i < cnt) {
                uint32_t b = binB[((size_t)row * BINBCAP + i) * 2 + 0];
                uint32_t idx = binB[((size_t)row * BINBCAP + i) * 2 + 1];
                key = ((uint64_t)(uint32_t)(~b) << 32) | idx;   // value desc, idx asc
            }
            sk[i] = key;
        }
        __syncthreads();
        for (int k = 2; k <= N; k <<= 1) {
            for (int j = k >> 1; j > 0; j >>= 1) {
                for (int i = threadIdx.x; i < N; i += 256) {
                    int ixj = i ^ j;
                    if (ixj > i) {
                        uint64_t A = sk[i], Bv = sk[ixj];
                        bool up = ((i & k) == 0);
                        if (up ? (A > Bv) : (A < Bv)) { sk[i] = Bv; sk[ixj] = A; }
                    }
                }
                __syncthreads();
            }
        }
        take = min(need, cnt);
    }
    int filled = (Bq < 0) ? cum : (cab + take);
    for (int slot = threadIdx.x; slot < LPAD; slot += 256) {
        uint64_t key;
        if (slot >= TOPK) key = ~0ULL;
        else {
            uint32_t bits = 0, idx = 0;
            if (slot < filled) {
                if (slot < cab) {
                    uint2 rr = ((const uint2*)outCand)[(size_t)row * TOPK + slot];
                    bits = rr.x; idx = rr.y;
                } else {
                    uint64_t wv = sk[slot - cab];
                    bits = ~((uint32_t)(wv >> 32));
                    idx = (uint32_t)(wv & 0xFFFFFFFFu);
                }
            }
            uint32_t be = 0;
            if (bits != 0) {
                float bc[4]; int cc; bool ne;
                decode_entry(P, img, lvl, idx, bc, &cc, &ne);
                if (ne) be = bits;
            }
            key = ((uint64_t)(uint32_t)(~be) << 24) | ((uint64_t)lvl << 21) | (uint64_t)idx;
        }
        kk[slot] = key;
    }
    __syncthreads();
    for (int k = 2; k <= LPAD; k <<= 1) {
        for (int j = k >> 1; j > 0; j >>= 1) {
            for (int i = threadIdx.x; i < LPAD; i += 256) {
                int ixj = i ^ j;
                if (ixj > i) {
                    uint64_t A = kk[i], Bv = kk[ixj];
                    bool up = ((i & k) == 0);
                    if (up ? (A > Bv) : (A < Bv)) { kk[i] = Bv; kk[ixj] = A; }
                }
            }
            __syncthreads();
        }
    }
    uint64_t* g = keys + (size_t)blk * LPAD;
    for (int i = threadIdx.x; i < LPAD; i += 256) g[i] = kk[i];
}

// ---- K5 (fused merge+prep): rank-merge 5 sorted lists, decode, write ----
// Exact: keys never tie cross-list (key embeds lvl); within-list rank uses
// position, so ranks form a bijection onto [0, 5000).
__global__ __launch_bounds__(1024) void k_merge(Params P, const uint64_t* keys,
                                                float4* boff, float* area, float4* bclip,
                                                float* scs, int* clss,
                                                uint8_t* keepB, uint8_t* clsB) {
    __shared__ uint64_t sl[NLEV * LPAD];   // 40 KB
    int img = blockIdx.x;
    const uint64_t* g = keys + (size_t)img * NLEV * LPAD;
    for (int i = threadIdx.x; i < NLEV * LPAD; i += 1024) sl[i] = g[i];
    __syncthreads();
    const int gb = img * MTOT;
    for (int e = threadIdx.x; e < NLEV * LPAD; e += 1024) {
        int l = e >> 10, i = e & (LPAD - 1);
        if (i >= TOPK) continue;           // sentinels sort to tail, never placed
        uint64_t K = sl[e];
        int rank = i;
#pragma unroll
        for (int l2 = 0; l2 < NLEV; l2++) {
            if (l2 == l) continue;
            const uint64_t* s2 = &sl[l2 << 10];
            int lo = 0, hi = TOPK;
            while (lo < hi) {
                int mid = (lo + hi) >> 1;
                if (s2[mid] < K) lo = mid + 1; else hi = mid;
            }
            rank += lo;
        }
        uint32_t bits = ~((uint32_t)(K >> 24));
        int lvl = (int)((K >> 21) & 7);
        uint32_t idx = (uint32_t)(K & 0x1FFFFF);
        float bc[4]; int cc; bool ne;
        decode_entry(P, img, lvl, idx, bc, &cc, &ne);
        float sc = 0.0f;
        if (bits != 0) {
            float s = __uint_as_float(bits);
            sc = sqrtf(fmaxf(s, 1e-12f));
        }
        float off = (float)cc * 2000.0f;
        float b0 = bc[0] + off, b1 = bc[1] + off, b2 = bc[2] + off, b3 = bc[3] + off;
        int t = gb + rank;
        boff[t] = make_float4(b0, b1, b2, b3);
        area[t] = (b2 - b0) * (b3 - b1);
        bclip[t] = make_float4(bc[0], bc[1], bc[2], bc[3]);
        scs[t] = sc;
        clss[t] = cc;
        keepB[t] = 0;
        clsB[t] = (sc != 0.0f) ? (uint8_t)cc : (uint8_t)0xFF;   // 0xFF = invalid
    }
}

// ---- K6: per-(img,class) greedy NMS; byte-map bucket build (L1-resident) ----
// Cross-class IoU is exactly 0 (offset 2000 > max coord 1216), so greedy
// keep/suppress decomposes exactly by class; bucket preserves rank order.
__global__ __launch_bounds__(64) void k_cnms(const float4* boff, const float* area,
                                             const uint8_t* clsB, uint8_t* keepB) {
    __shared__ float sx1[CCAP], sy1[CCAP], sx2[CCAP], sy2[CCAP], sar[CCAP];
    __shared__ uint16_t ranks[CCAP];
    int img = blockIdx.x / NCLS;
    int cls = blockIdx.x - img * NCLS;
    int lane = threadIdx.x;
    const int gb = img * MTOT;

    int n = 0;
    const uchar4* cp = (const uchar4*)(clsB + gb);      // 1250 uchar4 = 5 KB
    for (int base = 0; base < 1250; base += 64) {
        int q = base + lane;
        uchar4 cv = (q < 1250) ? cp[q] : make_uchar4(255, 255, 255, 255);
#pragma unroll
        for (int b = 0; b < 4; b++) {
            int cb = (b == 0) ? cv.x : (b == 1) ? cv.y : (b == 2) ? cv.z : cv.w;
            bool pred = (cb == cls);
            uint64_t mask = __ballot(pred);
            int pos = n + (int)__popcll(mask & ((1ULL << lane) - 1ULL));
            if (pred && pos < CCAP) ranks[pos] = (uint16_t)(q * 4 + b);
            n += (int)__popcll(mask);
        }
    }
    n = min(n, CCAP);
    __syncthreads();
    if (n == 0) return;

    for (int i = lane; i < n; i += 64) {
        int t = ranks[i];
        float4 b = boff[gb + t];
        sx1[i] = b.x; sy1[i] = b.y; sx2[i] = b.z; sy2[i] = b.w;
        sar[i] = area[gb + t];
    }
    __syncthreads();

    uint64_t m[CCAP / 64];
#pragma unroll
    for (int c = 0; c < CCAP / 64; c++) m[c] = 0ULL;
#pragma unroll
    for (int c = 0; c < CCAP / 64; c++) {
        if (c * 64 >= n) break;
        for (int ii = 0; ii < 64; ii++) {
            int i = c * 64 + ii;
            if (i >= n) break;
            if ((m[c] >> ii) & 1ULL) continue;
            float bx1 = sx1[i], by1 = sy1[i], bx2 = sx2[i], by2 = sy2[i], bai = sar[i];
            if (lane == 0) keepB[gb + ranks[i]] = 1;
#pragma unroll
            for (int c2 = 0; c2 < CCAP / 64; c2++) {
                if (c2 < c) continue;               // j > i pruning (const-folds)
                if (c2 * 64 >= n) break;
                int j = c2 * 64 + lane;
                float xx1 = fmaxf(bx1, sx1[j]), yy1 = fmaxf(by1, sy1[j]);
                float xx2 = fminf(bx2, sx2[j]), yy2 = fminf(by2, sy2[j]);
                float inter = fmaxf(xx2 - xx1, 0.0f) * fmaxf(yy2 - yy1, 0.0f);
                float iou = inter / (bai + sar[j] - inter + 1e-9f);
                bool pr = (j > i) && (j < n) && (iou > 0.6f);
                m[c2] |= __ballot(pr);
            }
        }
    }
}

// ---- K7: per-image output: first 100 kept (rank order) + filler ----
__global__ __launch_bounds__(64) void k_out(const float4* bclip, const float* scs,
                                            const int* clss, const uint8_t* keepB, float* out) {
    __shared__ int keptIdx[OUTK];
    int img = blockIdx.x;
    int lane = threadIdx.x;
    const int gb = img * MTOT;
    int kc = 0;
    for (int base = 0; base < MTOT && kc < OUTK; base += 64) {
        int t = base + lane;
        bool pred = (t < MTOT) && (keepB[gb + t] != 0);
        uint64_t mask = __ballot(pred);
        int pos = kc + (int)__popcll(mask & ((1ULL << lane) - 1ULL));
        if (pred && pos < OUTK) keptIdx[pos] = t;
        kc = min(kc + (int)__popcll(mask), OUTK);
    }
    for (int base = 0; base < MTOT && kc < OUTK; base += 64) {
        int t = base + lane;
        bool pred = (t < MTOT) && (keepB[gb + t] == 0);
        uint64_t mask = __ballot(pred);
        int pos = kc + (int)__popcll(mask & ((1ULL << lane) - 1ULL));
        if (pred && pos < OUTK) keptIdx[pos] = t | (1 << 30);
        kc = min(kc + (int)__popcll(mask), OUTK);
    }
    __syncthreads();
    for (int t = lane; t < OUTK; t += 64) {
        int ke = keptIdx[t];
        bool fil = (ke >> 30) & 1;
        int e = ke & 0x3FFFFFFF;
        float4 b = bclip[gb + e];
        out[((size_t)img * OUTK + t) * 4 + 0] = b.x;
        out[((size_t)img * OUTK + t) * 4 + 1] = b.y;
        out[((size_t)img * OUTK + t) * 4 + 2] = b.z;
        out[((size_t)img * OUTK + t) * 4 + 3] = b.w;
        out[NIMG * OUTK * 4 + img * OUTK + t] = fil ? 0.0f : scs[gb + e];
        out[NIMG * OUTK * 4 + NIMG * OUTK + img * OUTK + t] = (float)clss[gb + e];
    }
}

extern "C" void kernel_launch(void* const* d_in, const int* in_sizes, int n_in,
                              void* d_out, int out_size, void* d_ws, size_t ws_size,
                              hipStream_t stream) {
    Params P;
    for (int l = 0; l < 5; l++) {
        P.cls[l] = (const float*)d_in[l * 3 + 0];
        P.reg[l] = (const float*)d_in[l * 3 + 1];
        P.anc[l] = (const float*)d_in[l * 3 + 2];
    }
    P.imsize = (const int*)d_in[15];

    char* w = (char*)d_ws;
    // Lifetime-aliased layout (total 6,717,184 bytes; proven ws >= 7.9 MB):
    //  region A [0..3,520,000): binB (K3->K4) | NMS arrays (K5->K7)
    uint32_t* binB     = (uint32_t*)(w + 0);        // 80*4096*8  = 2,621,440
    float4*   boff     = (float4*)(w + 0);          // 1,280,000
    float*    area     = (float*)(w + 1280000);     // 320,000 -> 1,600,000
    float4*   bclipb   = (float4*)(w + 1600000);    // 1,280,000 -> 2,880,000
    float*    scs      = (float*)(w + 2880000);     // 320,000 -> 3,200,000
    int*      clss     = (int*)(w + 3200000);       // 320,000 -> 3,520,000
    int*      sel      = (int*)(w + 3520000);       // 1,280 -> 3,521,280
    uint32_t* outCount = (uint32_t*)(w + 3521280);  // 320 -> 3,521,600
    uint32_t* binBCnt  = (uint32_t*)(w + 3521600);  // 320 -> 3,521,920 (contig w/ outCount)
    float*    T        = (float*)(w + 3521920);     // 1,152 -> 3,523,072
    uint32_t* hist     = (uint32_t*)(w + 3523072);  // 80*288*4 = 92,160 -> 3,615,232
    uint32_t* outCand  = (uint32_t*)(w + 3615232);  // 640,000 -> 4,255,232
    uint64_t* keys     = (uint64_t*)(w + 4255232);  // 16*5120*8 = 655,360 -> 4,910,592
    uint8_t*  keepB    = (uint8_t*)(w + 4910592);   // 80,000 -> 4,990,592
    uint8_t*  clsB     = (uint8_t*)(w + 4990592);   // 80,000 -> 5,070,592
    uint16_t* segMax16 = (uint16_t*)(w + 5070592);  // 3216*256*2 = 1,646,592 -> 6,717,184

    k_thr<<<80, 320, 0, stream>>>(T, hist, outCount);
    k_hist<<<NCHUNK, 256, 0, stream>>>(P, T, hist, segMax16);
    k_scan<<<80, 320, 0, stream>>>(hist, sel);
    k_pass2<<<NCHUNK, 256, 0, stream>>>(P, sel, T, segMax16, outCand, outCount, binB, binBCnt);
    k_selkr<<<NIMG * NLEV, 256, 0, stream>>>(P, outCand, sel, binBCnt, binB, keys);
    k_merge<<<NIMG, 1024, 0, stream>>>(P, keys, boff, area, bclipb, scs, clss, keepB, clsB);
    k_cnms<<<NIMG * NCLS, 64, 0, stream>>>(boff, area, clsB, keepB);
    k_out<<<NIMG, 64, 0, stream>>>(bclipb, scs, clss, keepB, (float*)d_out);
}

// Round 11
// 242.736 us; speedup vs baseline: 1.0668x; 1.0618x over previous
//
#include <hip/hip_runtime.h>
#include <stdint.h>
#include <math.h>

#define NLEV 5
#define NIMG 16
#define NCLS 80
#define TOPK 1000
#define MTOT 5000
#define LPAD 1024
#define BINBCAP 4096
#define NBINS 288
#define BIN0 7846
#define OUTK 100
#define CHUNK 8192
#define NCHUNK 3216
#define PCAP_MAIN 1024
#define PCAP_BND 2048
#define CCAP 512

__device__ __constant__ int c_HW[NLEV]   = {15200, 3800, 950, 247, 70};
__device__ __constant__ int c_E[NLEV]    = {1216000, 304000, 76000, 19760, 5600};
__device__ __constant__ int c_cpr[NLEV]  = {149, 38, 10, 3, 1};          // 8192-chunks per (img,level) row
__device__ __constant__ int c_cbase[NLEV + 1] = {0, 2384, 2992, 3152, 3200, 3216};

struct Params {
    const float* cls[NLEV];
    const float* reg[NLEV];
    const float* anc[NLEV];
    const int* imsize;
};

// ---- shared decode (must be used identically by k_selkr and k_merge) ----
__device__ inline void decode_entry(const Params& P, int img, int lvl, uint32_t idx,
                                    float bclip[4], int* cls_out, bool* nonempty) {
    int HW = c_HW[lvl];
    int loc = (int)idx / NCLS;
    int c = (int)idx - loc * NCLS;
    const float* a = P.anc[lvl] + 4 * loc;
    float a0 = a[0], a1 = a[1], a2 = a[2], a3 = a[3];
    const float* rg = P.reg[lvl] + (size_t)img * 4 * HW + loc;
    float d0 = rg[0], d1 = rg[HW], d2 = rg[2 * HW], d3 = rg[3 * HW];
    float w = a2 - a0 + 1.0f, h = a3 - a1 + 1.0f;
    float cx = a0 + 0.5f * w, cy = a1 + 0.5f * h;
    float dx = d0 / 10.0f, dy = d1 / 10.0f;
    const float SCALE_CLAMP = 4.135166556742356f;
    float dw = fminf(d2 / 5.0f, SCALE_CLAMP);
    float dh = fminf(d3 / 5.0f, SCALE_CLAMP);
    float pcx = dx * w + cx, pcy = dy * h + cy;
    float pw = (float)exp((double)dw) * w;
    float ph = (float)exp((double)dh) * h;
    float x1 = pcx - 0.5f * (pw - 1.0f), y1 = pcy - 0.5f * (ph - 1.0f);
    float x2 = pcx + 0.5f * (pw - 1.0f), y2 = pcy + 0.5f * (ph - 1.0f);
    float Hs = (float)P.imsize[img * 2 + 0];
    float Ws = (float)P.imsize[img * 2 + 1];
    float x1c = fminf(fmaxf(x1, 0.0f), Ws);
    float y1c = fminf(fmaxf(y1, 0.0f), Hs);
    float x2c = fminf(fmaxf(x2, 0.0f), Ws);
    float y2c = fminf(fmaxf(y2, 0.0f), Hs);
    bclip[0] = x1c; bclip[1] = y1c; bclip[2] = x2c; bclip[3] = y2c;
    *cls_out = c;
    *nonempty = ((x2c - x1c) > 0.0f) && ((y2c - y1c) > 0.0f);
}

__device__ inline float sigmoid_f(float x) {
    return (float)(1.0 / (1.0 + exp(-(double)x)));
}

// ordered-uint <-> float (monotone bijection) for threshold bisection
__device__ inline uint32_t f2o(float f) {
    uint32_t b = __float_as_uint(f);
    return (b & 0x80000000u) ? ~b : (b | 0x80000000u);
}
__device__ inline float o2f(uint32_t o) {
    uint32_t b = (o & 0x80000000u) ? (o & 0x7FFFFFFFu) : ~o;
    return __uint_as_float(b);
}

// chunk -> (level, img, element range) mapping shared by k_hist / k_pass2
__device__ inline void chunk_map(int bid, int* lvl, int* img, int* start, int* end) {
    int l = 0;
#pragma unroll
    for (int q = 1; q < NLEV; q++) if (bid >= c_cbase[q]) l = q;
    int r = bid - c_cbase[l];
    int cpr = c_cpr[l];
    int im = r / cpr;
    int ch = r - im * cpr;
    int E = c_E[l];
    int st = ch * CHUNK;
    *lvl = l; *img = im; *start = st; *end = min(st + CHUNK, E);
}

// ---- K0: thresholds T[b] + zero hist + zero counters (fused init) ----
__global__ __launch_bounds__(320) void k_thr(float* T, uint32_t* hist, uint32_t* cnts) {
    int b = blockIdx.x;
    int t = threadIdx.x;
    if (t < NBINS) hist[b * NBINS + t] = 0;
    if (b == 1 && t < 160) cnts[t] = 0;            // outCount[80] + binBCnt[80]
    if (b == 0 && t < NBINS) {
        uint32_t lo = f2o(-4.0f), hi = f2o(20.0f);
        while (hi - lo > 1u) {
            uint32_t mid = lo + ((hi - lo) >> 1);
            float xm = o2f(mid);
            float s = sigmoid_f(xm);
            bool pass = (s > 0.05f) && (((int)(__float_as_uint(s) >> 17) - BIN0) >= t);
            if (pass) hi = mid; else lo = mid;
        }
        float xr = o2f(hi);
        float sv = sigmoid_f(xr);
        bool ok = (sv > 0.05f) && (((int)(__float_as_uint(sv) >> 17) - BIN0) >= t);
        T[t] = ok ? xr : __uint_as_float(0x7F800000u);
    }
}

// ---- K1: per-chunk hist (coalesced loads) + shuffle segment-max u16 ----
// Segment s covers elements [32s, 32s+32) = float4s [8s, 8s+8). With
// coalesced f = u*256+tid, those 8 float4s sit in 8 adjacent lanes of one
// iteration: 3 shfl_xor fmax ops produce the segment max. u16 bound rounds
// UP (reconstructed >= true max), so pass2's skip never drops an element.
__global__ __launch_bounds__(256) void k_hist(Params P, const float* T, uint32_t* hist,
                                              uint16_t* segMax16) {
    __shared__ uint32_t lh[NBINS];
    __shared__ float sT[NBINS];
    int l, img, start, end;
    chunk_map(blockIdx.x, &l, &img, &start, &end);
    for (int b = threadIdx.x; b < NBINS; b += 256) { lh[b] = 0; sT[b] = T[b]; }
    __syncthreads();
    float t0 = sT[0];
    const float4* p = (const float4*)(P.cls[l] + (size_t)img * c_E[l] + start);
    int n4 = (end - start) >> 2;
#pragma unroll
    for (int u = 0; u < 8; u++) {
        int f = u * 256 + threadIdx.x;
        float4 x4 = (f < n4) ? p[f] : make_float4(-1e30f, -1e30f, -1e30f, -1e30f);
        float m4 = fmaxf(fmaxf(x4.x, x4.y), fmaxf(x4.z, x4.w));
        float sm = m4;
        sm = fmaxf(sm, __shfl_xor(sm, 1));
        sm = fmaxf(sm, __shfl_xor(sm, 2));
        sm = fmaxf(sm, __shfl_xor(sm, 4));
        if ((threadIdx.x & 7) == 0) {
            int s = u * 32 + (threadIdx.x >> 3);
            uint32_t mb = __float_as_uint(sm);
            uint16_t ub = (sm >= 0.0f) ? (uint16_t)((mb + 0xFFFFu) >> 16) : (uint16_t)(mb >> 16);
            segMax16[(size_t)blockIdx.x * 256 + s] = ub;
        }
        float xs[4] = {x4.x, x4.y, x4.z, x4.w};
#pragma unroll
        for (int k = 0; k < 4; k++) {
            float xv = xs[k];
            if (xv >= t0) {
                float se = 1.0f / (1.0f + __expf(-xv));   // estimator only
                int b = (int)(__float_as_uint(se) >> 17) - BIN0;
                b = min(max(b, 0), NBINS - 1);
                while (b > 0 && xv < sT[b]) b--;          // exact fix-up:
                while (b + 1 < NBINS && xv >= sT[b + 1]) b++;  // T[b]<=x<T[b+1]
                atomicAdd(&lh[b], 1u);
            }
        }
    }
    __syncthreads();
    int row = l * NIMG + img;
    for (int b = threadIdx.x; b < NBINS; b += 256) {
        uint32_t c = lh[b];
        if (c) atomicAdd(&hist[row * NBINS + b], c);
    }
}

// ---- K2: scan per-row histogram top-down for boundary bin ----
__global__ __launch_bounds__(320) void k_scan(const uint32_t* hist, int* sel) {
    __shared__ uint32_t lh[NBINS];
    int row = blockIdx.x;
    if (threadIdx.x < NBINS) lh[threadIdx.x] = hist[row * NBINS + threadIdx.x];
    __syncthreads();
    if (threadIdx.x == 0) {
        int cum = 0, B = -1, need = 0, cab = 0;
        for (int b = NBINS - 1; b >= 0; b--) {
            int c = (int)lh[b];
            if (cum + c >= TOPK) { B = b; cab = cum; need = TOPK - cum; break; }
            cum += c;
        }
        if (B < 0) { cab = cum; need = 0; }
        sel[row * 4 + 0] = B;
        sel[row * 4 + 1] = cab;
        sel[row * 4 + 2] = need;
        sel[row * 4 + 3] = cum;
    }
}

// ---- K3: compact candidates; block-compacted segment worklist ----
// Active segments (ub >= xt) are compacted into LDS; 256 threads then
// cooperatively process ns*8 float4 work items (8 threads per segment,
// coalesced 128B). Wave-level skip: inactive segments cost nothing.
__global__ __launch_bounds__(256) void k_pass2(Params P, const int* sel, const float* T,
                                               const uint16_t* segMax16,
                                               uint32_t* outCand, uint32_t* outCount,
                                               uint32_t* binB, uint32_t* binBCnt) {
    __shared__ uint64_t smain[PCAP_MAIN];
    __shared__ uint64_t sbnd[PCAP_BND];
    __shared__ uint32_t cnt2[2];
    __shared__ uint32_t base2[2];
    __shared__ uint16_t segs[256];
    __shared__ int nseg;
    int l, img, start, end;
    chunk_map(blockIdx.x, &l, &img, &start, &end);
    int row = l * NIMG + img;
    int B = sel[row * 4 + 0];
    float xt = T[max(B, 0)];
    int HW = c_HW[l];
    if (threadIdx.x < 2) cnt2[threadIdx.x] = 0;
    if (threadIdx.x == 0) nseg = 0;
    __syncthreads();
    uint16_t ub = segMax16[(size_t)blockIdx.x * 256 + threadIdx.x];
    if (__uint_as_float((uint32_t)ub << 16) >= xt) {
        int q = atomicAdd(&nseg, 1);
        segs[q] = (uint16_t)threadIdx.x;
    }
    __syncthreads();
    int ns = nseg;
    const float4* p = (const float4*)(P.cls[l] + (size_t)img * c_E[l] + start);
    int n4 = (end - start) >> 2;
    for (int wk = threadIdx.x; wk < ns * 8; wk += 256) {
        int si = (int)segs[wk >> 3];
        int fi = si * 8 + (wk & 7);          // float4 index in chunk
        if (fi >= n4) continue;
        float4 x4 = p[fi];
        float xs[4] = {x4.x, x4.y, x4.z, x4.w};
#pragma unroll
        for (int k = 0; k < 4; k++) {
            float xv = xs[k];
            if (xv >= xt) {                       // implies s>0.05f && bin>=B
                float s = sigmoid_f(xv);          // exact bits for the key
                uint32_t bits = __float_as_uint(s);
                int bin = (int)(bits >> 17) - BIN0;
                int q2 = start + fi * 4 + k;      // c*HW + p layout
                int c = q2 / HW;
                int pidx = q2 - c * HW;
                uint32_t idx = (uint32_t)(pidx * NCLS + c);
                uint64_t rec = ((uint64_t)bits << 32) | idx;
                if (bin > B) {
                    uint32_t lp = atomicAdd(&cnt2[0], 1u);
                    if (lp < PCAP_MAIN) smain[lp] = rec;   // cab<=999 -> never overflows
                    else {
                        uint32_t pos = atomicAdd(&outCount[row], 1u);
                        if (pos < TOPK)
                            ((uint2*)outCand)[(size_t)row * TOPK + pos] = make_uint2(bits, idx);
                    }
                } else {
                    uint32_t lp = atomicAdd(&cnt2[1], 1u);
                    if (lp < PCAP_BND) sbnd[lp] = rec;
                    else {
                        uint32_t p2 = atomicAdd(&binBCnt[row], 1u);
                        if (p2 < BINBCAP)
                            ((uint2*)binB)[(size_t)row * BINBCAP + p2] = make_uint2(bits, idx);
                    }
                }
            }
        }
    }
    __syncthreads();
    if (threadIdx.x == 0) base2[0] = atomicAdd(&outCount[row], min(cnt2[0], (uint32_t)PCAP_MAIN));
    if (threadIdx.x == 1) base2[1] = atomicAdd(&binBCnt[row], min(cnt2[1], (uint32_t)PCAP_BND));
    __syncthreads();
    uint32_t n0 = min(cnt2[0], (uint32_t)PCAP_MAIN);
    for (uint32_t i = threadIdx.x; i < n0; i += 256) {
        uint32_t pos = base2[0] + i;
        if (pos < TOPK) {
            uint64_t rr = smain[i];
            ((uint2*)outCand)[(size_t)row * TOPK + pos] = make_uint2((uint32_t)(rr >> 32), (uint32_t)rr);
        }
    }
    uint32_t n1 = min(cnt2[1], (uint32_t)PCAP_BND);
    for (uint32_t i = threadIdx.x; i < n1; i += 256) {
        uint32_t pos = base2[1] + i;
        if (pos < BINBCAP) {
            uint64_t rr = sbnd[i];
            ((uint2*)binB)[(size_t)row * BINBCAP + pos] = make_uint2((uint32_t)(rr >> 32), (uint32_t)rr);
        }
    }
}

// ---- K4 (fused selsort + keys + rsort): boundary sort in LDS, build 1024
//      keys (winners read from LDS, no global round-trip), sort, store ----
__global__ __launch_bounds__(256) void k_selkr(Params P, const uint32_t* outCand,
                                               const int* sel, const uint32_t* binBCnt,
                                               const uint32_t* binB, uint64_t* keys) {
    __shared__ uint64_t sk[BINBCAP];   // 32 KB: boundary-bin sort
    __shared__ uint64_t kk[LPAD];      // 8 KB: final key sort
    int blk = blockIdx.x;              // keys layout [img][lvl][1024]
    int img = blk / NLEV, lvl = blk - img * NLEV;
    int row = lvl * NIMG + img;
    int Bq = sel[row * 4 + 0], cab = sel[row * 4 + 1];
    int need = sel[row * 4 + 2], cum = sel[row * 4 + 3];
    int cnt = min((int)binBCnt[row], BINBCAP);
    int take = 0;
    if (need > 0) {
        int N = 64; while (N < cnt) N <<= 1;
        for (int i = threadIdx.x; i < N; i += 256) {
            uint64_t key = ~0ULL;
            if (i < cnt) {
                uint32_t b = binB[((size_t)row * BINBCAP + i) * 2 + 0];
                uint32_t idx = binB[((size_t)row * BINBCAP + i) * 2 + 1];
                key = ((uint64_t)(uint32_t)(~b) << 32) | idx;   // value desc, idx asc
            }
            sk[i] = key;
        }
        __syncthreads();
        for (int k = 2; k <= N; k <<= 1) {
            for (int j = k >> 1; j > 0; j >>= 1) {
                for (int i = threadIdx.x; i < N; i += 256) {
                    int ixj = i ^ j;
                    if (ixj > i) {
                        uint64_t A = sk[i], Bv = sk[ixj];
                        bool up = ((i & k) == 0);
                        if (up ? (A > Bv) : (A < Bv)) { sk[i] = Bv; sk[ixj] = A; }
                    }
                }
                __syncthreads();
            }
        }
        take = min(need, cnt);
    }
    int filled = (Bq < 0) ? cum : (cab + take);
    for (int slot = threadIdx.x; slot < LPAD; slot += 256) {
        uint64_t key;
        if (slot >= TOPK) key = ~0ULL;
        else {
            uint32_t bits = 0, idx = 0;
            if (slot < filled) {
                if (slot < cab) {
                    uint2 rr = ((const uint2*)outCand)[(size_t)row * TOPK + slot];
                    bits = rr.x; idx = rr.y;
                } else {
                    uint64_t wv = sk[slot - cab];
                    bits = ~((uint32_t)(wv >> 32));
                    idx = (uint32_t)(wv & 0xFFFFFFFFu);
                }
            }
            uint32_t be = 0;
            if (bits != 0) {
                float bc[4]; int cc; bool ne;
                decode_entry(P, img, lvl, idx, bc, &cc, &ne);
                if (ne) be = bits;
            }
            key = ((uint64_t)(uint32_t)(~be) << 24) | ((uint64_t)lvl << 21) | (uint64_t)idx;
        }
        kk[slot] = key;
    }
    __syncthreads();
    for (int k = 2; k <= LPAD; k <<= 1) {
        for (int j = k >> 1; j > 0; j >>= 1) {
            for (int i = threadIdx.x; i < LPAD; i += 256) {
                int ixj = i ^ j;
                if (ixj > i) {
                    uint64_t A = kk[i], Bv = kk[ixj];
                    bool up = ((i & k) == 0);
                    if (up ? (A > Bv) : (A < Bv)) { kk[i] = Bv; kk[ixj] = A; }
                }
            }
            __syncthreads();
        }
    }
    uint64_t* g = keys + (size_t)blk * LPAD;
    for (int i = threadIdx.x; i < LPAD; i += 256) g[i] = kk[i];
}

// ---- K5 (fused merge+prep): rank-merge 5 sorted lists, decode, write ----
// Exact: keys never tie cross-list (key embeds lvl); within-list rank uses
// position, so ranks form a bijection onto [0, 5000).
__global__ __launch_bounds__(1024) void k_merge(Params P, const uint64_t* keys,
                                                float4* boff, float* area, float4* bclip,
                                                float* scs, int* clss,
                                                uint8_t* keepB, uint8_t* clsB) {
    __shared__ uint64_t sl[NLEV * LPAD];   // 40 KB
    int img = blockIdx.x;
    const uint64_t* g = keys + (size_t)img * NLEV * LPAD;
    for (int i = threadIdx.x; i < NLEV * LPAD; i += 1024) sl[i] = g[i];
    __syncthreads();
    const int gb = img * MTOT;
    for (int e = threadIdx.x; e < NLEV * LPAD; e += 1024) {
        int l = e >> 10, i = e & (LPAD - 1);
        if (i >= TOPK) continue;           // sentinels sort to tail, never placed
        uint64_t K = sl[e];
        int rank = i;
#pragma unroll
        for (int l2 = 0; l2 < NLEV; l2++) {
            if (l2 == l) continue;
            const uint64_t* s2 = &sl[l2 << 10];
            int lo = 0, hi = TOPK;
            while (lo < hi) {
                int mid = (lo + hi) >> 1;
                if (s2[mid] < K) lo = mid + 1; else hi = mid;
            }
            rank += lo;
        }
        uint32_t bits = ~((uint32_t)(K >> 24));
        int lvl = (int)((K >> 21) & 7);
        uint32_t idx = (uint32_t)(K & 0x1FFFFF);
        float bc[4]; int cc; bool ne;
        decode_entry(P, img, lvl, idx, bc, &cc, &ne);
        float sc = 0.0f;
        if (bits != 0) {
            float s = __uint_as_float(bits);
            sc = sqrtf(fmaxf(s, 1e-12f));
        }
        float off = (float)cc * 2000.0f;
        float b0 = bc[0] + off, b1 = bc[1] + off, b2 = bc[2] + off, b3 = bc[3] + off;
        int t = gb + rank;
        boff[t] = make_float4(b0, b1, b2, b3);
        area[t] = (b2 - b0) * (b3 - b1);
        bclip[t] = make_float4(bc[0], bc[1], bc[2], bc[3]);
        scs[t] = sc;
        clss[t] = cc;
        keepB[t] = 0;
        clsB[t] = (sc != 0.0f) ? (uint8_t)cc : (uint8_t)0xFF;   // 0xFF = invalid
    }
}

// ---- K6: per-(img,class) greedy NMS; byte-map bucket build (L1-resident) ----
// Cross-class IoU is exactly 0 (offset 2000 > max coord 1216), so greedy
// keep/suppress decomposes exactly by class; bucket preserves rank order.
__global__ __launch_bounds__(64) void k_cnms(const float4* boff, const float* area,
                                             const uint8_t* clsB, uint8_t* keepB) {
    __shared__ float sx1[CCAP], sy1[CCAP], sx2[CCAP], sy2[CCAP], sar[CCAP];
    __shared__ uint16_t ranks[CCAP];
    int img = blockIdx.x / NCLS;
    int cls = blockIdx.x - img * NCLS;
    int lane = threadIdx.x;
    const int gb = img * MTOT;

    int n = 0;
    const uchar4* cp = (const uchar4*)(clsB + gb);      // 1250 uchar4 = 5 KB
    for (int base = 0; base < 1250; base += 64) {
        int q = base + lane;
        uchar4 cv = (q < 1250) ? cp[q] : make_uchar4(255, 255, 255, 255);
#pragma unroll
        for (int b = 0; b < 4; b++) {
            int cb = (b == 0) ? cv.x : (b == 1) ? cv.y : (b == 2) ? cv.z : cv.w;
            bool pred = (cb == cls);
            uint64_t mask = __ballot(pred);
            int pos = n + (int)__popcll(mask & ((1ULL << lane) - 1ULL));
            if (pred && pos < CCAP) ranks[pos] = (uint16_t)(q * 4 + b);
            n += (int)__popcll(mask);
        }
    }
    n = min(n, CCAP);
    __syncthreads();
    if (n == 0) return;

    for (int i = lane; i < n; i += 64) {
        int t = ranks[i];
        float4 b = boff[gb + t];
        sx1[i] = b.x; sy1[i] = b.y; sx2[i] = b.z; sy2[i] = b.w;
        sar[i] = area[gb + t];
    }
    __syncthreads();

    uint64_t m[CCAP / 64];
#pragma unroll
    for (int c = 0; c < CCAP / 64; c++) m[c] = 0ULL;
#pragma unroll
    for (int c = 0; c < CCAP / 64; c++) {
        if (c * 64 >= n) break;
        for (int ii = 0; ii < 64; ii++) {
            int i = c * 64 + ii;
            if (i >= n) break;
            if ((m[c] >> ii) & 1ULL) continue;
            float bx1 = sx1[i], by1 = sy1[i], bx2 = sx2[i], by2 = sy2[i], bai = sar[i];
            if (lane == 0) keepB[gb + ranks[i]] = 1;
#pragma unroll
            for (int c2 = 0; c2 < CCAP / 64; c2++) {
                if (c2 < c) continue;               // j > i pruning (const-folds)
                if (c2 * 64 >= n) break;
                int j = c2 * 64 + lane;
                float xx1 = fmaxf(bx1, sx1[j]), yy1 = fmaxf(by1, sy1[j]);
                float xx2 = fminf(bx2, sx2[j]), yy2 = fminf(by2, sy2[j]);
                float inter = fmaxf(xx2 - xx1, 0.0f) * fmaxf(yy2 - yy1, 0.0f);
                float iou = inter / (bai + sar[j] - inter + 1e-9f);
                bool pr = (j > i) && (j < n) && (iou > 0.6f);
                m[c2] |= __ballot(pr);
            }
        }
    }
}

// ---- K7: per-image output: first 100 kept (rank order) + filler ----
__global__ __launch_bounds__(64) void k_out(const float4* bclip, const float* scs,
                                            const int* clss, const uint8_t* keepB, float* out) {
    __shared__ int keptIdx[OUTK];
    int img = blockIdx.x;
    int lane = threadIdx.x;
    const int gb = img * MTOT;
    int kc = 0;
    for (int base = 0; base < MTOT && kc < OUTK; base += 64) {
        int t = base + lane;
        bool pred = (t < MTOT) && (keepB[gb + t] != 0);
        uint64_t mask = __ballot(pred);
        int pos = kc + (int)__popcll(mask & ((1ULL << lane) - 1ULL));
        if (pred && pos < OUTK) keptIdx[pos] = t;
        kc = min(kc + (int)__popcll(mask), OUTK);
    }
    for (int base = 0; base < MTOT && kc < OUTK; base += 64) {
        int t = base + lane;
        bool pred = (t < MTOT) && (keepB[gb + t] == 0);
        uint64_t mask = __ballot(pred);
        int pos = kc + (int)__popcll(mask & ((1ULL << lane) - 1ULL));
        if (pred && pos < OUTK) keptIdx[pos] = t | (1 << 30);
        kc = min(kc + (int)__popcll(mask), OUTK);
    }
    __syncthreads();
    for (int t = lane; t < OUTK; t += 64) {
        int ke = keptIdx[t];
        bool fil = (ke >> 30) & 1;
        int e = ke & 0x3FFFFFFF;
        float4 b = bclip[gb + e];
        out[((size_t)img * OUTK + t) * 4 + 0] = b.x;
        out[((size_t)img * OUTK + t) * 4 + 1] = b.y;
        out[((size_t)img * OUTK + t) * 4 + 2] = b.z;
        out[((size_t)img * OUTK + t) * 4 + 3] = b.w;
        out[NIMG * OUTK * 4 + img * OUTK + t] = fil ? 0.0f : scs[gb + e];
        out[NIMG * OUTK * 4 + NIMG * OUTK + img * OUTK + t] = (float)clss[gb + e];
    }
}

extern "C" void kernel_launch(void* const* d_in, const int* in_sizes, int n_in,
                              void* d_out, int out_size, void* d_ws, size_t ws_size,
                              hipStream_t stream) {
    Params P;
    for (int l = 0; l < 5; l++) {
        P.cls[l] = (const float*)d_in[l * 3 + 0];
        P.reg[l] = (const float*)d_in[l * 3 + 1];
        P.anc[l] = (const float*)d_in[l * 3 + 2];
    }
    P.imsize = (const int*)d_in[15];

    char* w = (char*)d_ws;
    // Lifetime-aliased layout (total 6,717,184 bytes; proven ws >= 7.9 MB):
    //  region A [0..3,520,000): binB (K3->K4) | NMS arrays (K5->K7)
    uint32_t* binB     = (uint32_t*)(w + 0);        // 80*4096*8  = 2,621,440
    float4*   boff     = (float4*)(w + 0);          // 1,280,000
    float*    area     = (float*)(w + 1280000);     // 320,000 -> 1,600,000
    float4*   bclipb   = (float4*)(w + 1600000);    // 1,280,000 -> 2,880,000
    float*    scs      = (float*)(w + 2880000);     // 320,000 -> 3,200,000
    int*      clss     = (int*)(w + 3200000);       // 320,000 -> 3,520,000
    int*      sel      = (int*)(w + 3520000);       // 1,280 -> 3,521,280
    uint32_t* outCount = (uint32_t*)(w + 3521280);  // 320 -> 3,521,600
    uint32_t* binBCnt  = (uint32_t*)(w + 3521600);  // 320 -> 3,521,920 (contig w/ outCount)
    float*    T        = (float*)(w + 3521920);     // 1,152 -> 3,523,072
    uint32_t* hist     = (uint32_t*)(w + 3523072);  // 80*288*4 = 92,160 -> 3,615,232
    uint32_t* outCand  = (uint32_t*)(w + 3615232);  // 640,000 -> 4,255,232
    uint64_t* keys     = (uint64_t*)(w + 4255232);  // 16*5120*8 = 655,360 -> 4,910,592
    uint8_t*  keepB    = (uint8_t*)(w + 4910592);   // 80,000 -> 4,990,592
    uint8_t*  clsB     = (uint8_t*)(w + 4990592);   // 80,000 -> 5,070,592
    uint16_t* segMax16 = (uint16_t*)(w + 5070592);  // 3216*256*2 = 1,646,592 -> 6,717,184

    k_thr<<<80, 320, 0, stream>>>(T, hist, outCount);
    k_hist<<<NCHUNK, 256, 0, stream>>>(P, T, hist, segMax16);
    k_scan<<<80, 320, 0, stream>>>(hist, sel);
    k_pass2<<<NCHUNK, 256, 0, stream>>>(P, sel, T, segMax16, outCand, outCount, binB, binBCnt);
    k_selkr<<<NIMG * NLEV, 256, 0, stream>>>(P, outCand, sel, binBCnt, binB, keys);
    k_merge<<<NIMG, 1024, 0, stream>>>(P, keys, boff, area, bclipb, scs, clss, keepB, clsB);
    k_cnms<<<NIMG * NCLS, 64, 0, stream>>>(boff, area, clsB, keepB);
    k_out<<<NIMG, 64, 0, stream>>>(bclipb, scs, clss, keepB, (float*)d_out);
}

// Round 12
// 204.018 us; speedup vs baseline: 1.2692x; 1.1898x over previous
//
#include <hip/hip_runtime.h>
#include <stdint.h>
#include <math.h>

#define NLEV 5
#define NIMG 16
#define NCLS 80
#define TOPK 1000
#define MTOT 5000
#define LPAD 1024
#define BINBCAP 4096
#define NBINS 288
#define BIN0 7846
#define OUTK 100
#define CHUNK 8192
#define NCHUNK 3216
#define PCAP_MAIN 1024
#define PCAP_BND 2048
#define CCAP 512

__device__ __constant__ int c_HW[NLEV]   = {15200, 3800, 950, 247, 70};
__device__ __constant__ int c_E[NLEV]    = {1216000, 304000, 76000, 19760, 5600};
__device__ __constant__ int c_cpr[NLEV]  = {149, 38, 10, 3, 1};          // 8192-chunks per (img,level) row
__device__ __constant__ int c_cbase[NLEV + 1] = {0, 2384, 2992, 3152, 3200, 3216};

struct Params {
    const float* cls[NLEV];
    const float* reg[NLEV];
    const float* anc[NLEV];
    const int* imsize;
};

// ---- shared decode (must be used identically by k_selkr and k_merge) ----
__device__ inline void decode_entry(const Params& P, int img, int lvl, uint32_t idx,
                                    float bclip[4], int* cls_out, bool* nonempty) {
    int HW = c_HW[lvl];
    int loc = (int)idx / NCLS;
    int c = (int)idx - loc * NCLS;
    const float* a = P.anc[lvl] + 4 * loc;
    float a0 = a[0], a1 = a[1], a2 = a[2], a3 = a[3];
    const float* rg = P.reg[lvl] + (size_t)img * 4 * HW + loc;
    float d0 = rg[0], d1 = rg[HW], d2 = rg[2 * HW], d3 = rg[3 * HW];
    float w = a2 - a0 + 1.0f, h = a3 - a1 + 1.0f;
    float cx = a0 + 0.5f * w, cy = a1 + 0.5f * h;
    float dx = d0 / 10.0f, dy = d1 / 10.0f;
    const float SCALE_CLAMP = 4.135166556742356f;
    float dw = fminf(d2 / 5.0f, SCALE_CLAMP);
    float dh = fminf(d3 / 5.0f, SCALE_CLAMP);
    float pcx = dx * w + cx, pcy = dy * h + cy;
    float pw = (float)exp((double)dw) * w;
    float ph = (float)exp((double)dh) * h;
    float x1 = pcx - 0.5f * (pw - 1.0f), y1 = pcy - 0.5f * (ph - 1.0f);
    float x2 = pcx + 0.5f * (pw - 1.0f), y2 = pcy + 0.5f * (ph - 1.0f);
    float Hs = (float)P.imsize[img * 2 + 0];
    float Ws = (float)P.imsize[img * 2 + 1];
    float x1c = fminf(fmaxf(x1, 0.0f), Ws);
    float y1c = fminf(fmaxf(y1, 0.0f), Hs);
    float x2c = fminf(fmaxf(x2, 0.0f), Ws);
    float y2c = fminf(fmaxf(y2, 0.0f), Hs);
    bclip[0] = x1c; bclip[1] = y1c; bclip[2] = x2c; bclip[3] = y2c;
    *cls_out = c;
    *nonempty = ((x2c - x1c) > 0.0f) && ((y2c - y1c) > 0.0f);
}

__device__ inline float sigmoid_f(float x) {
    return (float)(1.0 / (1.0 + exp(-(double)x)));
}

// ordered-uint <-> float (monotone bijection) for threshold bisection
__device__ inline uint32_t f2o(float f) {
    uint32_t b = __float_as_uint(f);
    return (b & 0x80000000u) ? ~b : (b | 0x80000000u);
}
__device__ inline float o2f(uint32_t o) {
    uint32_t b = (o & 0x80000000u) ? (o & 0x7FFFFFFFu) : ~o;
    return __uint_as_float(b);
}

// chunk -> (level, img, element range) mapping shared by k_hist / k_pass2
__device__ inline void chunk_map(int bid, int* lvl, int* img, int* start, int* end) {
    int l = 0;
#pragma unroll
    for (int q = 1; q < NLEV; q++) if (bid >= c_cbase[q]) l = q;
    int r = bid - c_cbase[l];
    int cpr = c_cpr[l];
    int im = r / cpr;
    int ch = r - im * cpr;
    int E = c_E[l];
    int st = ch * CHUNK;
    *lvl = l; *img = im; *start = st; *end = min(st + CHUNK, E);
}

// ---- K0: thresholds T[b] + zero hist + zero counters (fused init) ----
__global__ __launch_bounds__(320) void k_thr(float* T, uint32_t* hist, uint32_t* cnts) {
    int b = blockIdx.x;
    int t = threadIdx.x;
    if (t < NBINS) hist[b * NBINS + t] = 0;
    if (b == 1 && t < 160) cnts[t] = 0;            // outCount[80] + binBCnt[80]
    if (b == 0 && t < NBINS) {
        uint32_t lo = f2o(-4.0f), hi = f2o(20.0f);
        while (hi - lo > 1u) {
            uint32_t mid = lo + ((hi - lo) >> 1);
            float xm = o2f(mid);
            float s = sigmoid_f(xm);
            bool pass = (s > 0.05f) && (((int)(__float_as_uint(s) >> 17) - BIN0) >= t);
            if (pass) hi = mid; else lo = mid;
        }
        float xr = o2f(hi);
        float sv = sigmoid_f(xr);
        bool ok = (sv > 0.05f) && (((int)(__float_as_uint(sv) >> 17) - BIN0) >= t);
        T[t] = ok ? xr : __uint_as_float(0x7F800000u);
    }
}

// ---- K1: per-chunk hist (coalesced loads) + shuffle segment-max u16 ----
// Segment s covers elements [32s, 32s+32) = float4s [8s, 8s+8). With
// coalesced f = u*256+tid, those 8 float4s sit in 8 adjacent lanes of one
// iteration: 3 shfl_xor fmax ops produce the segment max. u16 bound rounds
// UP (reconstructed >= true max), so pass2's skip never drops an element.
__global__ __launch_bounds__(256) void k_hist(Params P, const float* T, uint32_t* hist,
                                              uint16_t* segMax16) {
    __shared__ uint32_t lh[NBINS];
    __shared__ float sT[NBINS];
    int l, img, start, end;
    chunk_map(blockIdx.x, &l, &img, &start, &end);
    for (int b = threadIdx.x; b < NBINS; b += 256) { lh[b] = 0; sT[b] = T[b]; }
    __syncthreads();
    float t0 = sT[0];
    const float4* p = (const float4*)(P.cls[l] + (size_t)img * c_E[l] + start);
    int n4 = (end - start) >> 2;
#pragma unroll
    for (int u = 0; u < 8; u++) {
        int f = u * 256 + threadIdx.x;
        float4 x4 = (f < n4) ? p[f] : make_float4(-1e30f, -1e30f, -1e30f, -1e30f);
        float m4 = fmaxf(fmaxf(x4.x, x4.y), fmaxf(x4.z, x4.w));
        float sm = m4;
        sm = fmaxf(sm, __shfl_xor(sm, 1));
        sm = fmaxf(sm, __shfl_xor(sm, 2));
        sm = fmaxf(sm, __shfl_xor(sm, 4));
        if ((threadIdx.x & 7) == 0) {
            int s = u * 32 + (threadIdx.x >> 3);
            uint32_t mb = __float_as_uint(sm);
            uint16_t ub = (sm >= 0.0f) ? (uint16_t)((mb + 0xFFFFu) >> 16) : (uint16_t)(mb >> 16);
            segMax16[(size_t)blockIdx.x * 256 + s] = ub;
        }
        float xs[4] = {x4.x, x4.y, x4.z, x4.w};
#pragma unroll
        for (int k = 0; k < 4; k++) {
            float xv = xs[k];
            if (xv >= t0) {
                float se = 1.0f / (1.0f + __expf(-xv));   // estimator only
                int b = (int)(__float_as_uint(se) >> 17) - BIN0;
                b = min(max(b, 0), NBINS - 1);
                while (b > 0 && xv < sT[b]) b--;          // exact fix-up:
                while (b + 1 < NBINS && xv >= sT[b + 1]) b++;  // T[b]<=x<T[b+1]
                atomicAdd(&lh[b], 1u);
            }
        }
    }
    __syncthreads();
    int row = l * NIMG + img;
    for (int b = threadIdx.x; b < NBINS; b += 256) {
        uint32_t c = lh[b];
        if (c) atomicAdd(&hist[row * NBINS + b], c);
    }
}

// ---- K2: scan per-row histogram top-down for boundary bin ----
__global__ __launch_bounds__(320) void k_scan(const uint32_t* hist, int* sel) {
    __shared__ uint32_t lh[NBINS];
    int row = blockIdx.x;
    if (threadIdx.x < NBINS) lh[threadIdx.x] = hist[row * NBINS + threadIdx.x];
    __syncthreads();
    if (threadIdx.x == 0) {
        int cum = 0, B = -1, need = 0, cab = 0;
        for (int b = NBINS - 1; b >= 0; b--) {
            int c = (int)lh[b];
            if (cum + c >= TOPK) { B = b; cab = cum; need = TOPK - cum; break; }
            cum += c;
        }
        if (B < 0) { cab = cum; need = 0; }
        sel[row * 4 + 0] = B;
        sel[row * 4 + 1] = cab;
        sel[row * 4 + 2] = need;
        sel[row * 4 + 3] = cum;
    }
}

// ---- K3: compact candidates; block-compacted segment worklist ----
__global__ __launch_bounds__(256) void k_pass2(Params P, const int* sel, const float* T,
                                               const uint16_t* segMax16,
                                               uint32_t* outCand, uint32_t* outCount,
                                               uint32_t* binB, uint32_t* binBCnt) {
    __shared__ uint64_t smain[PCAP_MAIN];
    __shared__ uint64_t sbnd[PCAP_BND];
    __shared__ uint32_t cnt2[2];
    __shared__ uint32_t base2[2];
    __shared__ uint16_t segs[256];
    __shared__ int nseg;
    int l, img, start, end;
    chunk_map(blockIdx.x, &l, &img, &start, &end);
    int row = l * NIMG + img;
    int B = sel[row * 4 + 0];
    float xt = T[max(B, 0)];
    int HW = c_HW[l];
    if (threadIdx.x < 2) cnt2[threadIdx.x] = 0;
    if (threadIdx.x == 0) nseg = 0;
    __syncthreads();
    uint16_t ub = segMax16[(size_t)blockIdx.x * 256 + threadIdx.x];
    if (__uint_as_float((uint32_t)ub << 16) >= xt) {
        int q = atomicAdd(&nseg, 1);
        segs[q] = (uint16_t)threadIdx.x;
    }
    __syncthreads();
    int ns = nseg;
    const float4* p = (const float4*)(P.cls[l] + (size_t)img * c_E[l] + start);
    int n4 = (end - start) >> 2;
    for (int wk = threadIdx.x; wk < ns * 8; wk += 256) {
        int si = (int)segs[wk >> 3];
        int fi = si * 8 + (wk & 7);          // float4 index in chunk
        if (fi >= n4) continue;
        float4 x4 = p[fi];
        float xs[4] = {x4.x, x4.y, x4.z, x4.w};
#pragma unroll
        for (int k = 0; k < 4; k++) {
            float xv = xs[k];
            if (xv >= xt) {                       // implies s>0.05f && bin>=B
                float s = sigmoid_f(xv);          // exact bits for the key
                uint32_t bits = __float_as_uint(s);
                int bin = (int)(bits >> 17) - BIN0;
                int q2 = start + fi * 4 + k;      // c*HW + p layout
                int c = q2 / HW;
                int pidx = q2 - c * HW;
                uint32_t idx = (uint32_t)(pidx * NCLS + c);
                uint64_t rec = ((uint64_t)bits << 32) | idx;
                if (bin > B) {
                    uint32_t lp = atomicAdd(&cnt2[0], 1u);
                    if (lp < PCAP_MAIN) smain[lp] = rec;   // cab<=999 -> never overflows
                    else {
                        uint32_t pos = atomicAdd(&outCount[row], 1u);
                        if (pos < TOPK)
                            ((uint2*)outCand)[(size_t)row * TOPK + pos] = make_uint2(bits, idx);
                    }
                } else {
                    uint32_t lp = atomicAdd(&cnt2[1], 1u);
                    if (lp < PCAP_BND) sbnd[lp] = rec;
                    else {
                        uint32_t p2 = atomicAdd(&binBCnt[row], 1u);
                        if (p2 < BINBCAP)
                            ((uint2*)binB)[(size_t)row * BINBCAP + p2] = make_uint2(bits, idx);
                    }
                }
            }
        }
    }
    __syncthreads();
    if (threadIdx.x == 0) base2[0] = atomicAdd(&outCount[row], min(cnt2[0], (uint32_t)PCAP_MAIN));
    if (threadIdx.x == 1) base2[1] = atomicAdd(&binBCnt[row], min(cnt2[1], (uint32_t)PCAP_BND));
    __syncthreads();
    uint32_t n0 = min(cnt2[0], (uint32_t)PCAP_MAIN);
    for (uint32_t i = threadIdx.x; i < n0; i += 256) {
        uint32_t pos = base2[0] + i;
        if (pos < TOPK) {
            uint64_t rr = smain[i];
            ((uint2*)outCand)[(size_t)row * TOPK + pos] = make_uint2((uint32_t)(rr >> 32), (uint32_t)rr);
        }
    }
    uint32_t n1 = min(cnt2[1], (uint32_t)PCAP_BND);
    for (uint32_t i = threadIdx.x; i < n1; i += 256) {
        uint32_t pos = base2[1] + i;
        if (pos < BINBCAP) {
            uint64_t rr = sbnd[i];
            ((uint2*)binB)[(size_t)row * BINBCAP + pos] = make_uint2((uint32_t)(rr >> 32), (uint32_t)rr);
        }
    }
}

// ---- K4 (fused selsort + keys + rsort), 1024 threads for latency hiding ----
__global__ __launch_bounds__(1024) void k_selkr(Params P, const uint32_t* outCand,
                                                const int* sel, const uint32_t* binBCnt,
                                                const uint32_t* binB, uint64_t* keys) {
    __shared__ uint64_t sk[BINBCAP];   // 32 KB: boundary-bin sort
    __shared__ uint64_t kk[LPAD];      // 8 KB: final key sort
    int blk = blockIdx.x;              // keys layout [img][lvl][1024]
    int img = blk / NLEV, lvl = blk - img * NLEV;
    int row = lvl * NIMG + img;
    int Bq = sel[row * 4 + 0], cab = sel[row * 4 + 1];
    int need = sel[row * 4 + 2], cum = sel[row * 4 + 3];
    int cnt = min((int)binBCnt[row], BINBCAP);
    int take = 0;
    if (need > 0) {
        int N = 64; while (N < cnt) N <<= 1;
        for (int i = threadIdx.x; i < N; i += 1024) {
            uint64_t key = ~0ULL;
            if (i < cnt) {
                uint32_t b = binB[((size_t)row * BINBCAP + i) * 2 + 0];
                uint32_t idx = binB[((size_t)row * BINBCAP + i) * 2 + 1];
                key = ((uint64_t)(uint32_t)(~b) << 32) | idx;   // value desc, idx asc
            }
            sk[i] = key;
        }
        __syncthreads();
        for (int k = 2; k <= N; k <<= 1) {
            for (int j = k >> 1; j > 0; j >>= 1) {
                for (int i = threadIdx.x; i < N; i += 1024) {
                    int ixj = i ^ j;
                    if (ixj > i) {
                        uint64_t A = sk[i], Bv = sk[ixj];
                        bool up = ((i & k) == 0);
                        if (up ? (A > Bv) : (A < Bv)) { sk[i] = Bv; sk[ixj] = A; }
                    }
                }
                __syncthreads();
            }
        }
        take = min(need, cnt);
    }
    int filled = (Bq < 0) ? cum : (cab + take);
    for (int slot = threadIdx.x; slot < LPAD; slot += 1024) {
        uint64_t key;
        if (slot >= TOPK) key = ~0ULL;
        else {
            uint32_t bits = 0, idx = 0;
            if (slot < filled) {
                if (slot < cab) {
                    uint2 rr = ((const uint2*)outCand)[(size_t)row * TOPK + slot];
                    bits = rr.x; idx = rr.y;
                } else {
                    uint64_t wv = sk[slot - cab];
                    bits = ~((uint32_t)(wv >> 32));
                    idx = (uint32_t)(wv & 0xFFFFFFFFu);
                }
            }
            uint32_t be = 0;
            if (bits != 0) {
                float bc[4]; int cc; bool ne;
                decode_entry(P, img, lvl, idx, bc, &cc, &ne);
                if (ne) be = bits;
            }
            key = ((uint64_t)(uint32_t)(~be) << 24) | ((uint64_t)lvl << 21) | (uint64_t)idx;
        }
        kk[slot] = key;
    }
    __syncthreads();
    for (int k = 2; k <= LPAD; k <<= 1) {
        for (int j = k >> 1; j > 0; j >>= 1) {
            for (int i = threadIdx.x; i < LPAD; i += 1024) {
                int ixj = i ^ j;
                if (ixj > i) {
                    uint64_t A = kk[i], Bv = kk[ixj];
                    bool up = ((i & k) == 0);
                    if (up ? (A > Bv) : (A < Bv)) { kk[i] = Bv; kk[ixj] = A; }
                }
            }
            __syncthreads();
        }
    }
    uint64_t* g = keys + (size_t)blk * LPAD;
    for (int i = threadIdx.x; i < LPAD; i += 1024) g[i] = kk[i];
}

// ---- K5 (fused merge+prep): 4 blocks/image; each loads all 5 lists,
//      processes a quarter of the entries. Ranks are a bijection. ----
__global__ __launch_bounds__(1024) void k_merge(Params P, const uint64_t* keys,
                                                float4* boff, float* area, float4* bclip,
                                                float* scs, int* clss,
                                                uint8_t* keepB, uint8_t* clsB) {
    __shared__ uint64_t sl[NLEV * LPAD];   // 40 KB
    int img = blockIdx.x >> 2;
    int part = blockIdx.x & 3;
    const uint64_t* g = keys + (size_t)img * NLEV * LPAD;
    for (int i = threadIdx.x; i < NLEV * LPAD; i += 1024) sl[i] = g[i];
    __syncthreads();
    const int gb = img * MTOT;
    int e0 = part * (NLEV * LPAD / 4);
    int e1 = e0 + (NLEV * LPAD / 4);
    for (int e = e0 + threadIdx.x; e < e1; e += 1024) {
        int l = e >> 10, i = e & (LPAD - 1);
        if (i >= TOPK) continue;           // sentinels sort to tail, never placed
        uint64_t K = sl[e];
        int rank = i;
#pragma unroll
        for (int l2 = 0; l2 < NLEV; l2++) {
            if (l2 == l) continue;
            const uint64_t* s2 = &sl[l2 << 10];
            int lo = 0, hi = TOPK;
            while (lo < hi) {
                int mid = (lo + hi) >> 1;
                if (s2[mid] < K) lo = mid + 1; else hi = mid;
            }
            rank += lo;
        }
        uint32_t bits = ~((uint32_t)(K >> 24));
        int lvl = (int)((K >> 21) & 7);
        uint32_t idx = (uint32_t)(K & 0x1FFFFF);
        float bc[4]; int cc; bool ne;
        decode_entry(P, img, lvl, idx, bc, &cc, &ne);
        float sc = 0.0f;
        if (bits != 0) {
            float s = __uint_as_float(bits);
            sc = sqrtf(fmaxf(s, 1e-12f));
        }
        float off = (float)cc * 2000.0f;
        float b0 = bc[0] + off, b1 = bc[1] + off, b2 = bc[2] + off, b3 = bc[3] + off;
        int t = gb + rank;
        boff[t] = make_float4(b0, b1, b2, b3);
        area[t] = (b2 - b0) * (b3 - b1);
        bclip[t] = make_float4(bc[0], bc[1], bc[2], bc[3]);
        scs[t] = sc;
        clss[t] = cc;
        keepB[t] = 0;
        clsB[t] = (sc != 0.0f) ? (uint8_t)cc : (uint8_t)0xFF;   // 0xFF = invalid
    }
}

// ---- K6: per-(img,class) greedy NMS; byte-map bucket build (L1-resident) ----
__global__ __launch_bounds__(64) void k_cnms(const float4* boff, const float* area,
                                             const uint8_t* clsB, uint8_t* keepB) {
    __shared__ float sx1[CCAP], sy1[CCAP], sx2[CCAP], sy2[CCAP], sar[CCAP];
    __shared__ uint16_t ranks[CCAP];
    int img = blockIdx.x / NCLS;
    int cls = blockIdx.x - img * NCLS;
    int lane = threadIdx.x;
    const int gb = img * MTOT;

    int n = 0;
    const uchar4* cp = (const uchar4*)(clsB + gb);      // 1250 uchar4 = 5 KB
    for (int base = 0; base < 1250; base += 64) {
        int q = base + lane;
        uchar4 cv = (q < 1250) ? cp[q] : make_uchar4(255, 255, 255, 255);
#pragma unroll
        for (int b = 0; b < 4; b++) {
            int cb = (b == 0) ? cv.x : (b == 1) ? cv.y : (b == 2) ? cv.z : cv.w;
            bool pred = (cb == cls);
            uint64_t mask = __ballot(pred);
            int pos = n + (int)__popcll(mask & ((1ULL << lane) - 1ULL));
            if (pred && pos < CCAP) ranks[pos] = (uint16_t)(q * 4 + b);
            n += (int)__popcll(mask);
        }
    }
    n = min(n, CCAP);
    __syncthreads();
    if (n == 0) return;

    for (int i = lane; i < n; i += 64) {
        int t = ranks[i];
        float4 b = boff[gb + t];
        sx1[i] = b.x; sy1[i] = b.y; sx2[i] = b.z; sy2[i] = b.w;
        sar[i] = area[gb + t];
    }
    __syncthreads();

    uint64_t m[CCAP / 64];
#pragma unroll
    for (int c = 0; c < CCAP / 64; c++) m[c] = 0ULL;
#pragma unroll
    for (int c = 0; c < CCAP / 64; c++) {
        if (c * 64 >= n) break;
        for (int ii = 0; ii < 64; ii++) {
            int i = c * 64 + ii;
            if (i >= n) break;
            if ((m[c] >> ii) & 1ULL) continue;
            float bx1 = sx1[i], by1 = sy1[i], bx2 = sx2[i], by2 = sy2[i], bai = sar[i];
            if (lane == 0) keepB[gb + ranks[i]] = 1;
#pragma unroll
            for (int c2 = 0; c2 < CCAP / 64; c2++) {
                if (c2 < c) continue;               // j > i pruning (const-folds)
                if (c2 * 64 >= n) break;
                int j = c2 * 64 + lane;
                float xx1 = fmaxf(bx1, sx1[j]), yy1 = fmaxf(by1, sy1[j]);
                float xx2 = fminf(bx2, sx2[j]), yy2 = fminf(by2, sy2[j]);
                float inter = fmaxf(xx2 - xx1, 0.0f) * fmaxf(yy2 - yy1, 0.0f);
                float iou = inter / (bai + sar[j] - inter + 1e-9f);
                bool pr = (j > i) && (j < n) && (iou > 0.6f);
                m[c2] |= __ballot(pr);
            }
        }
    }
}

// ---- K7: per-image output: first 100 kept (rank order) + filler ----
__global__ __launch_bounds__(64) void k_out(const float4* bclip, const float* scs,
                                            const int* clss, const uint8_t* keepB, float* out) {
    __shared__ int keptIdx[OUTK];
    int img = blockIdx.x;
    int lane = threadIdx.x;
    const int gb = img * MTOT;
    int kc = 0;
    for (int base = 0; base < MTOT && kc < OUTK; base += 64) {
        int t = base + lane;
        bool pred = (t < MTOT) && (keepB[gb + t] != 0);
        uint64_t mask = __ballot(pred);
        int pos = kc + (int)__popcll(mask & ((1ULL << lane) - 1ULL));
        if (pred && pos < OUTK) keptIdx[pos] = t;
        kc = min(kc + (int)__popcll(mask), OUTK);
    }
    for (int base = 0; base < MTOT && kc < OUTK; base += 64) {
        int t = base + lane;
        bool pred = (t < MTOT) && (keepB[gb + t] == 0);
        uint64_t mask = __ballot(pred);
        int pos = kc + (int)__popcll(mask & ((1ULL << lane) - 1ULL));
        if (pred && pos < OUTK) keptIdx[pos] = t | (1 << 30);
        kc = min(kc + (int)__popcll(mask), OUTK);
    }
    __syncthreads();
    for (int t = lane; t < OUTK; t += 64) {
        int ke = keptIdx[t];
        bool fil = (ke >> 30) & 1;
        int e = ke & 0x3FFFFFFF;
        float4 b = bclip[gb + e];
        out[((size_t)img * OUTK + t) * 4 + 0] = b.x;
        out[((size_t)img * OUTK + t) * 4 + 1] = b.y;
        out[((size_t)img * OUTK + t) * 4 + 2] = b.z;
        out[((size_t)img * OUTK + t) * 4 + 3] = b.w;
        out[NIMG * OUTK * 4 + img * OUTK + t] = fil ? 0.0f : scs[gb + e];
        out[NIMG * OUTK * 4 + NIMG * OUTK + img * OUTK + t] = (float)clss[gb + e];
    }
}

extern "C" void kernel_launch(void* const* d_in, const int* in_sizes, int n_in,
                              void* d_out, int out_size, void* d_ws, size_t ws_size,
                              hipStream_t stream) {
    Params P;
    for (int l = 0; l < 5; l++) {
        P.cls[l] = (const float*)d_in[l * 3 + 0];
        P.reg[l] = (const float*)d_in[l * 3 + 1];
        P.anc[l] = (const float*)d_in[l * 3 + 2];
    }
    P.imsize = (const int*)d_in[15];

    char* w = (char*)d_ws;
    // Lifetime-aliased layout (total 6,717,184 bytes; proven ws >= 7.9 MB):
    //  region A [0..3,520,000): binB (K3->K4) | NMS arrays (K5->K7)
    uint32_t* binB     = (uint32_t*)(w + 0);        // 80*4096*8  = 2,621,440
    float4*   boff     = (float4*)(w + 0);          // 1,280,000
    float*    area     = (float*)(w + 1280000);     // 320,000 -> 1,600,000
    float4*   bclipb   = (float4*)(w + 1600000);    // 1,280,000 -> 2,880,000
    float*    scs      = (float*)(w + 2880000);     // 320,000 -> 3,200,000
    int*      clss     = (int*)(w + 3200000);       // 320,000 -> 3,520,000
    int*      sel      = (int*)(w + 3520000);       // 1,280 -> 3,521,280
    uint32_t* outCount = (uint32_t*)(w + 3521280);  // 320 -> 3,521,600
    uint32_t* binBCnt  = (uint32_t*)(w + 3521600);  // 320 -> 3,521,920 (contig w/ outCount)
    float*    T        = (float*)(w + 3521920);     // 1,152 -> 3,523,072
    uint32_t* hist     = (uint32_t*)(w + 3523072);  // 80*288*4 = 92,160 -> 3,615,232
    uint32_t* outCand  = (uint32_t*)(w + 3615232);  // 640,000 -> 4,255,232
    uint64_t* keys     = (uint64_t*)(w + 4255232);  // 16*5120*8 = 655,360 -> 4,910,592
    uint8_t*  keepB    = (uint8_t*)(w + 4910592);   // 80,000 -> 4,990,592
    uint8_t*  clsB     = (uint8_t*)(w + 4990592);   // 80,000 -> 5,070,592
    uint16_t* segMax16 = (uint16_t*)(w + 5070592);  // 3216*256*2 = 1,646,592 -> 6,717,184

    k_thr<<<80, 320, 0, stream>>>(T, hist, outCount);
    k_hist<<<NCHUNK, 256, 0, stream>>>(P, T, hist, segMax16);
    k_scan<<<80, 320, 0, stream>>>(hist, sel);
    k_pass2<<<NCHUNK, 256, 0, stream>>>(P, sel, T, segMax16, outCand, outCount, binB, binBCnt);
    k_selkr<<<NIMG * NLEV, 1024, 0, stream>>>(P, outCand, sel, binBCnt, binB, keys);
    k_merge<<<NIMG * 4, 1024, 0, stream>>>(P, keys, boff, area, bclipb, scs, clss, keepB, clsB);
    k_cnms<<<NIMG * NCLS, 64, 0, stream>>>(boff, area, clsB, keepB);
    k_out<<<NIMG, 64, 0, stream>>>(bclipb, scs, clss, keepB, (float*)d_out);
}